// Round 2
// baseline (980.465 us; speedup 1.0000x reference)
//
#include <hip/hip_runtime.h>

// ---------------------------------------------------------------------------
// ProjectionResBlock: x[N,128] -> relu(bn3(einsum(gather(relu(bn1(x@w1)))
//                      ,w2)@w3... ) + bnp(x@wp))
// N=200000, C_IN=128, MID=64, C_OUT=256, K=27. Output f32 [N,256].
// Strategy: bf16 MFMA (16x16x32) for all GEMMs, f32 accum; BN stats via
// per-wave partials -> coalesced reduce -> finalize (fold into scale/bias).
// Final kernel fuses conv3+bn3+proj+bnp+relu via acc=(s3/sp)*y3 + yp trick.
// ---------------------------------------------------------------------------

typedef __bf16 bf16_8 __attribute__((ext_vector_type(8)));
typedef float f32x4 __attribute__((ext_vector_type(4)));

#define NN 200000
#define NBLK 3125          // N / 64

// ---- workspace byte offsets (all 16B-aligned) ----
#define OFF_W1T   (size_t)0               // bf16 [64][128]    16384
#define OFF_WPT   (size_t)16384           // bf16 [256][128]   65536
#define OFF_W2T   (size_t)81920           // bf16 [27][64][64] 221184
#define OFF_W3T   (size_t)303104          // bf16 [256][64]    32768
#define OFF_Y1    (size_t)335872          // bf16 [N][64]      25600000
#define OFF_H1    (size_t)25935872        // bf16 [N][64]
#define OFF_Y2    (size_t)51535872        // bf16 [N][64]
#define OFF_H2B   (size_t)77135872        // bf16 [N][64]
#define OFF_P1    (size_t)102735872       // f32 [12500][640]  32000000
#define OFF_P2    (size_t)134735872       // f32 [6250][128]   3200000
#define OFF_P3    (size_t)137935872       // f32 [12500][512]  25600000
#define OFF_COEF  (size_t)163535872       // f32 [1536]        6144
#define OFF_PA1   (size_t)163542016       // f32 [125][640]    320000
#define OFF_PA2   (size_t)163862016       // f32 [125][128]    64000
#define OFF_PA3   (size_t)163926016       // f32 [125][512]    256000
// total ~164.2 MB

// coef float indices: s1=0, t1=64, s2=128, t2=192, sp=256, tp=512,
//                     cr(=s3/sp)=768, cb(=t3+tp)=1280

// ---------------------------------------------------------------------------
// K0: transpose weights to bf16 (wT[out][in])
// ---------------------------------------------------------------------------
__global__ void k_prep(const float* __restrict__ w1, const float* __restrict__ w2,
                       const float* __restrict__ w3, const float* __restrict__ wp,
                       __bf16* __restrict__ w1T, __bf16* __restrict__ w2T,
                       __bf16* __restrict__ w3T, __bf16* __restrict__ wpT) {
    int i = blockIdx.x * 256 + threadIdx.x;
    if (i < 128 * 64)  { int r = i / 64,  c = i % 64;  w1T[c * 128 + r] = (__bf16)w1[i]; }
    if (i < 27 * 64 * 64) {
        int k = i / 4096, rc = i % 4096, c = rc / 64, o = rc % 64;
        w2T[((size_t)(k * 64 + o)) * 64 + c] = (__bf16)w2[i];
    }
    if (i < 64 * 256)  { int r = i / 256, c = i % 256; w3T[c * 64 + r]  = (__bf16)w3[i]; }
    if (i < 128 * 256) { int r = i / 256, c = i % 256; wpT[c * 128 + r] = (__bf16)wp[i]; }
}

// ---------------------------------------------------------------------------
// K1: y1 = x @ w1 (store bf16) ; column sums/sumsq for [w1|wp] (320 cols)
// block = 64 rows, 4 waves x 16 rows. ntiles: 0-3 -> w1 (stored), 4-19 -> wp
// ---------------------------------------------------------------------------
__global__ __launch_bounds__(256) void k1(const float* __restrict__ x,
                                          const __bf16* __restrict__ w1T,
                                          const __bf16* __restrict__ wpT,
                                          __bf16* __restrict__ y1,
                                          float* __restrict__ p1) {
    int blk = blockIdx.x;
    int wave = threadIdx.x >> 6, lane = threadIdx.x & 63;
    int l15 = lane & 15, lg = lane >> 4;
    int row = blk * 64 + wave * 16 + l15;

    const float* xr = x + (size_t)row * 128 + lg * 8;
    bf16_8 a[4];
#pragma unroll
    for (int ks = 0; ks < 4; ks++) {
        float4 f0 = *(const float4*)(xr + ks * 32);
        float4 f1 = *(const float4*)(xr + ks * 32 + 4);
        bf16_8 t;
        t[0] = (__bf16)f0.x; t[1] = (__bf16)f0.y; t[2] = (__bf16)f0.z; t[3] = (__bf16)f0.w;
        t[4] = (__bf16)f1.x; t[5] = (__bf16)f1.y; t[6] = (__bf16)f1.z; t[7] = (__bf16)f1.w;
        a[ks] = t;
    }

    f32x4 acc[20];
#pragma unroll
    for (int nt = 0; nt < 20; nt++) acc[nt] = (f32x4){0.f, 0.f, 0.f, 0.f};

#pragma unroll
    for (int nt = 0; nt < 20; nt++) {
        const __bf16* bt = (nt < 4)
            ? (w1T + (size_t)(nt * 16 + l15) * 128)
            : (wpT + (size_t)((nt - 4) * 16 + l15) * 128);
#pragma unroll
        for (int ks = 0; ks < 4; ks++) {
            bf16_8 b = *(const bf16_8*)(bt + ks * 32 + lg * 8);
            acc[nt] = __builtin_amdgcn_mfma_f32_16x16x32_bf16(a[ks], b, acc[nt], 0, 0, 0);
        }
    }

    // store y1 (ntiles 0..3)
#pragma unroll
    for (int nt = 0; nt < 4; nt++) {
#pragma unroll
        for (int r4 = 0; r4 < 4; r4++) {
            int gr = blk * 64 + wave * 16 + lg * 4 + r4;
            y1[(size_t)gr * 64 + nt * 16 + l15] = (__bf16)acc[nt][r4];
        }
    }

    // per-wave column partials (sum, sumsq) over this wave's 16 rows
    float* prow = p1 + ((size_t)blk * 4 + wave) * 640;
#pragma unroll
    for (int nt = 0; nt < 20; nt++) {
        float s = 0.f, q = 0.f;
#pragma unroll
        for (int r4 = 0; r4 < 4; r4++) { float v = acc[nt][r4]; s += v; q += v * v; }
        s += __shfl_xor(s, 16); s += __shfl_xor(s, 32);
        q += __shfl_xor(q, 16); q += __shfl_xor(q, 32);
        if (lane < 16) { prow[nt * 16 + l15] = s; prow[320 + nt * 16 + l15] = q; }
    }
}

// ---------------------------------------------------------------------------
// coalesced tree reduction of partials: out[b][c] = sum over chunk rows
// ---------------------------------------------------------------------------
__global__ void k_red(const float* __restrict__ part, float* __restrict__ outp,
                      int nrows, int chunk) {
    int width = blockDim.x;
    int b = blockIdx.x, t = threadIdx.x;
    int r0 = b * chunk, r1 = r0 + chunk;
    if (r1 > nrows) r1 = nrows;
    float s = 0.f;
    for (int r = r0; r < r1; r++) s += part[(size_t)r * width + t];
    outp[(size_t)b * width + t] = s;
}

// ---------------------------------------------------------------------------
// finalize: mean/var -> scale/bias (optionally fused with projection coeffs)
// ---------------------------------------------------------------------------
__global__ void k_fin(const float* __restrict__ psum, const float* __restrict__ psq,
                      int nrows, int rowstride,
                      const float* __restrict__ g, const float* __restrict__ b,
                      float* __restrict__ s_out, float* __restrict__ t_out,
                      const float* __restrict__ fsp, const float* __restrict__ ftp) {
    int c = blockIdx.x;
    float s = 0.f, q = 0.f;
    for (int r = threadIdx.x; r < nrows; r += blockDim.x) {
        size_t o = (size_t)r * rowstride + c;
        s += psum[o]; q += psq[o];
    }
#pragma unroll
    for (int off = 32; off; off >>= 1) { s += __shfl_xor(s, off); q += __shfl_xor(q, off); }
    __shared__ float ls[4], lq[4];
    int wv = threadIdx.x >> 6;
    if ((threadIdx.x & 63) == 0) { ls[wv] = s; lq[wv] = q; }
    __syncthreads();
    if (threadIdx.x == 0) {
        s = ls[0] + ls[1] + ls[2] + ls[3];
        q = lq[0] + lq[1] + lq[2] + lq[3];
        float m = s * (1.f / (float)NN);
        float v = q * (1.f / (float)NN) - m * m;
        float rs = rsqrtf(v + 1e-3f);
        float sc = g[c] * rs;
        float tb = b[c] - m * sc;
        if (fsp) { sc = sc / fsp[c]; tb = tb + ftp[c]; }
        s_out[c] = sc; t_out[c] = tb;
    }
}

// ---------------------------------------------------------------------------
// K_h1: h1 = relu(s1*y1 + t1) as bf16 (elementwise, 8 elems/thread)
// ---------------------------------------------------------------------------
__global__ __launch_bounds__(256) void k_h1(const __bf16* __restrict__ y1,
                                            const float* __restrict__ coef,
                                            __bf16* __restrict__ h1) {
    int i = blockIdx.x * 256 + threadIdx.x;   // 0 .. N*64/8
    int c0 = (i * 8) & 63;
    bf16_8 v = *(const bf16_8*)(y1 + (size_t)i * 8);
    bf16_8 o;
#pragma unroll
    for (int j = 0; j < 8; j++) {
        float f = (float)v[j] * coef[c0 + j] + coef[64 + c0 + j];
        o[j] = (__bf16)fmaxf(f, 0.f);
    }
    *(bf16_8*)(h1 + (size_t)i * 8) = o;
}

// ---------------------------------------------------------------------------
// K3: y2[n,o] = sum_k sum_c h1[neigh[n,k],c] * w2[k,c,o]  (27-neigh einsum)
// block = 64 rows, 2 waves x 32 rows (2 mtiles); neigh staged in LDS.
// ---------------------------------------------------------------------------
__global__ __launch_bounds__(128) void k3(const int* __restrict__ neigh,
                                          const __bf16* __restrict__ h1,
                                          const __bf16* __restrict__ w2T,
                                          __bf16* __restrict__ y2,
                                          float* __restrict__ p2) {
    __shared__ int nl[64 * 27];
    int blk = blockIdx.x, tid = threadIdx.x;
    for (int i = tid; i < 64 * 27; i += 128) nl[i] = neigh[(size_t)blk * (64 * 27) + i];
    __syncthreads();

    int wave = tid >> 6, lane = tid & 63, l15 = lane & 15, lg = lane >> 4;
    f32x4 acc[2][4];
#pragma unroll
    for (int m = 0; m < 2; m++)
#pragma unroll
        for (int nt = 0; nt < 4; nt++) acc[m][nt] = (f32x4){0.f, 0.f, 0.f, 0.f};

    for (int k = 0; k < 27; k++) {
        bf16_8 a[2][2];
#pragma unroll
        for (int m = 0; m < 2; m++) {
            int r = wave * 32 + m * 16 + l15;
            int idx = nl[r * 27 + k];
            const __bf16* hp = h1 + (size_t)idx * 64 + lg * 8;
            a[m][0] = *(const bf16_8*)(hp);
            a[m][1] = *(const bf16_8*)(hp + 32);
        }
#pragma unroll
        for (int nt = 0; nt < 4; nt++) {
            const __bf16* bp = w2T + (size_t)(k * 64 + nt * 16 + l15) * 64 + lg * 8;
            bf16_8 b0 = *(const bf16_8*)(bp);
            bf16_8 b1 = *(const bf16_8*)(bp + 32);
            acc[0][nt] = __builtin_amdgcn_mfma_f32_16x16x32_bf16(a[0][0], b0, acc[0][nt], 0, 0, 0);
            acc[0][nt] = __builtin_amdgcn_mfma_f32_16x16x32_bf16(a[0][1], b1, acc[0][nt], 0, 0, 0);
            acc[1][nt] = __builtin_amdgcn_mfma_f32_16x16x32_bf16(a[1][0], b0, acc[1][nt], 0, 0, 0);
            acc[1][nt] = __builtin_amdgcn_mfma_f32_16x16x32_bf16(a[1][1], b1, acc[1][nt], 0, 0, 0);
        }
    }

#pragma unroll
    for (int m = 0; m < 2; m++)
#pragma unroll
        for (int nt = 0; nt < 4; nt++)
#pragma unroll
            for (int r4 = 0; r4 < 4; r4++) {
                int gr = blk * 64 + wave * 32 + m * 16 + lg * 4 + r4;
                y2[(size_t)gr * 64 + nt * 16 + l15] = (__bf16)acc[m][nt][r4];
            }

    float* prow = p2 + ((size_t)blk * 2 + wave) * 128;
#pragma unroll
    for (int nt = 0; nt < 4; nt++) {
        float s = 0.f, q = 0.f;
#pragma unroll
        for (int m = 0; m < 2; m++)
#pragma unroll
            for (int r4 = 0; r4 < 4; r4++) { float v = acc[m][nt][r4]; s += v; q += v * v; }
        s += __shfl_xor(s, 16); s += __shfl_xor(s, 32);
        q += __shfl_xor(q, 16); q += __shfl_xor(q, 32);
        if (lane < 16) { prow[nt * 16 + l15] = s; prow[64 + nt * 16 + l15] = q; }
    }
}

// ---------------------------------------------------------------------------
// K5: h2b = relu(s2*y2+t2) bf16 (stored) ; y3 = h2b @ w3 -> column partials
// block = 64 rows, 4 waves x 16 rows; 16 ntiles (256 cols)
// ---------------------------------------------------------------------------
__global__ __launch_bounds__(256) void k5(const __bf16* __restrict__ y2,
                                          const float* __restrict__ coef,
                                          const __bf16* __restrict__ w3T,
                                          __bf16* __restrict__ h2b,
                                          float* __restrict__ p3) {
    int blk = blockIdx.x;
    int wave = threadIdx.x >> 6, lane = threadIdx.x & 63;
    int l15 = lane & 15, lg = lane >> 4;
    int row = blk * 64 + wave * 16 + l15;

    bf16_8 a[2];
#pragma unroll
    for (int ks = 0; ks < 2; ks++) {
        bf16_8 v = *(const bf16_8*)(y2 + (size_t)row * 64 + ks * 32 + lg * 8);
        bf16_8 t;
#pragma unroll
        for (int j = 0; j < 8; j++) {
            int c = ks * 32 + lg * 8 + j;
            float f = (float)v[j] * coef[128 + c] + coef[192 + c];
            t[j] = (__bf16)fmaxf(f, 0.f);
        }
        a[ks] = t;
        *(bf16_8*)(h2b + (size_t)row * 64 + ks * 32 + lg * 8) = t;
    }

    f32x4 acc[16];
#pragma unroll
    for (int nt = 0; nt < 16; nt++) acc[nt] = (f32x4){0.f, 0.f, 0.f, 0.f};

#pragma unroll
    for (int nt = 0; nt < 16; nt++) {
        const __bf16* bp = w3T + (size_t)(nt * 16 + l15) * 64 + lg * 8;
        bf16_8 b0 = *(const bf16_8*)(bp);
        bf16_8 b1 = *(const bf16_8*)(bp + 32);
        acc[nt] = __builtin_amdgcn_mfma_f32_16x16x32_bf16(a[0], b0, acc[nt], 0, 0, 0);
        acc[nt] = __builtin_amdgcn_mfma_f32_16x16x32_bf16(a[1], b1, acc[nt], 0, 0, 0);
    }

    float* prow = p3 + ((size_t)blk * 4 + wave) * 512;
#pragma unroll
    for (int nt = 0; nt < 16; nt++) {
        float s = 0.f, q = 0.f;
#pragma unroll
        for (int r4 = 0; r4 < 4; r4++) { float v = acc[nt][r4]; s += v; q += v * v; }
        s += __shfl_xor(s, 16); s += __shfl_xor(s, 32);
        q += __shfl_xor(q, 16); q += __shfl_xor(q, 32);
        if (lane < 16) { prow[nt * 16 + l15] = s; prow[256 + nt * 16 + l15] = q; }
    }
}

// ---------------------------------------------------------------------------
// K7: out = relu( s3*(h2b@w3) + t3 + sp*(x@wp) + tp )
//    via acc = (s3/sp)*(h2b@w3); acc += x@wp; out = relu(sp*acc + (t3+tp))
// ---------------------------------------------------------------------------
__global__ __launch_bounds__(256) void k7(const float* __restrict__ x,
                                          const __bf16* __restrict__ h2b,
                                          const __bf16* __restrict__ w3T,
                                          const __bf16* __restrict__ wpT,
                                          const float* __restrict__ coef,
                                          float* __restrict__ out) {
    int blk = blockIdx.x;
    int wave = threadIdx.x >> 6, lane = threadIdx.x & 63;
    int l15 = lane & 15, lg = lane >> 4;
    int row = blk * 64 + wave * 16 + l15;

    bf16_8 ah[2];
    ah[0] = *(const bf16_8*)(h2b + (size_t)row * 64 + lg * 8);
    ah[1] = *(const bf16_8*)(h2b + (size_t)row * 64 + 32 + lg * 8);

    f32x4 acc[16];
#pragma unroll
    for (int nt = 0; nt < 16; nt++) acc[nt] = (f32x4){0.f, 0.f, 0.f, 0.f};

#pragma unroll
    for (int nt = 0; nt < 16; nt++) {
        const __bf16* bp = w3T + (size_t)(nt * 16 + l15) * 64 + lg * 8;
        bf16_8 b0 = *(const bf16_8*)(bp);
        bf16_8 b1 = *(const bf16_8*)(bp + 32);
        acc[nt] = __builtin_amdgcn_mfma_f32_16x16x32_bf16(ah[0], b0, acc[nt], 0, 0, 0);
        acc[nt] = __builtin_amdgcn_mfma_f32_16x16x32_bf16(ah[1], b1, acc[nt], 0, 0, 0);
    }

    // scale by cr = s3/sp (per column)
#pragma unroll
    for (int nt = 0; nt < 16; nt++) {
        float r = coef[768 + nt * 16 + l15];
        acc[nt] *= r;
    }

    // += x @ wp
    const float* xr = x + (size_t)row * 128 + lg * 8;
    bf16_8 ax[4];
#pragma unroll
    for (int ks = 0; ks < 4; ks++) {
        float4 f0 = *(const float4*)(xr + ks * 32);
        float4 f1 = *(const float4*)(xr + ks * 32 + 4);
        bf16_8 t;
        t[0] = (__bf16)f0.x; t[1] = (__bf16)f0.y; t[2] = (__bf16)f0.z; t[3] = (__bf16)f0.w;
        t[4] = (__bf16)f1.x; t[5] = (__bf16)f1.y; t[6] = (__bf16)f1.z; t[7] = (__bf16)f1.w;
        ax[ks] = t;
    }
#pragma unroll
    for (int nt = 0; nt < 16; nt++) {
        const __bf16* bp = wpT + (size_t)(nt * 16 + l15) * 128 + lg * 8;
#pragma unroll
        for (int ks = 0; ks < 4; ks++) {
            bf16_8 b = *(const bf16_8*)(bp + ks * 32);
            acc[nt] = __builtin_amdgcn_mfma_f32_16x16x32_bf16(ax[ks], b, acc[nt], 0, 0, 0);
        }
    }

    // epilogue: out = relu(sp*acc + (t3+tp))
#pragma unroll
    for (int nt = 0; nt < 16; nt++) {
        int c = nt * 16 + l15;
        float cs = coef[256 + c];
        float cb = coef[1280 + c];
#pragma unroll
        for (int r4 = 0; r4 < 4; r4++) {
            int gr = blk * 64 + wave * 16 + lg * 4 + r4;
            out[(size_t)gr * 256 + c] = fmaxf(acc[nt][r4] * cs + cb, 0.f);
        }
    }
}

// ---------------------------------------------------------------------------
extern "C" void kernel_launch(void* const* d_in, const int* in_sizes, int n_in,
                              void* d_out, int out_size, void* d_ws, size_t ws_size,
                              hipStream_t stream) {
    const float* x     = (const float*)d_in[0];
    const int*   neigh = (const int*)d_in[1];
    const float* w1 = (const float*)d_in[3];
    const float* g1 = (const float*)d_in[4];
    const float* b1 = (const float*)d_in[5];
    const float* w2 = (const float*)d_in[6];
    const float* g2 = (const float*)d_in[7];
    const float* b2 = (const float*)d_in[8];
    const float* w3 = (const float*)d_in[9];
    const float* g3 = (const float*)d_in[10];
    const float* b3 = (const float*)d_in[11];
    const float* wp = (const float*)d_in[12];
    const float* gp = (const float*)d_in[13];
    const float* bp = (const float*)d_in[14];
    float* out = (float*)d_out;

    char* ws = (char*)d_ws;
    __bf16* w1T = (__bf16*)(ws + OFF_W1T);
    __bf16* wpT = (__bf16*)(ws + OFF_WPT);
    __bf16* w2T = (__bf16*)(ws + OFF_W2T);
    __bf16* w3T = (__bf16*)(ws + OFF_W3T);
    __bf16* y1  = (__bf16*)(ws + OFF_Y1);
    __bf16* h1  = (__bf16*)(ws + OFF_H1);
    __bf16* y2  = (__bf16*)(ws + OFF_Y2);
    __bf16* h2b = (__bf16*)(ws + OFF_H2B);
    float* p1   = (float*)(ws + OFF_P1);
    float* p2   = (float*)(ws + OFF_P2);
    float* p3   = (float*)(ws + OFF_P3);
    float* coef = (float*)(ws + OFF_COEF);
    float* pA1  = (float*)(ws + OFF_PA1);
    float* pA2  = (float*)(ws + OFF_PA2);
    float* pA3  = (float*)(ws + OFF_PA3);

    // stage 0: weights -> bf16 transposed
    k_prep<<<432, 256, 0, stream>>>(w1, w2, w3, wp, w1T, w2T, w3T, wpT);

    // stage 1: y1 = x@w1 (+ stats for w1 and wp branches)
    k1<<<NBLK, 256, 0, stream>>>(x, w1T, wpT, y1, p1);
    k_red<<<125, 640, 0, stream>>>(p1, pA1, 12500, 100);
    k_fin<<<64, 256, 0, stream>>>(pA1, pA1 + 320, 125, 640, g1, b1,
                                  coef + 0, coef + 64, nullptr, nullptr);
    k_fin<<<256, 256, 0, stream>>>(pA1 + 64, pA1 + 384, 125, 640, gp, bp,
                                   coef + 256, coef + 512, nullptr, nullptr);

    // stage 1b: h1 = relu(bn1(y1))
    k_h1<<<6250, 256, 0, stream>>>(y1, coef, h1);

    // stage 2: gather einsum
    k3<<<NBLK, 128, 0, stream>>>(neigh, h1, w2T, y2, p2);
    k_red<<<125, 128, 0, stream>>>(p2, pA2, 6250, 50);
    k_fin<<<64, 256, 0, stream>>>(pA2, pA2 + 64, 125, 128, g2, b2,
                                  coef + 128, coef + 192, nullptr, nullptr);

    // stage 3: h2b = relu(bn2(y2)); y3 stats
    k5<<<NBLK, 256, 0, stream>>>(y2, coef, w3T, h2b, p3);
    k_red<<<125, 512, 0, stream>>>(p3, pA3, 12500, 100);
    k_fin<<<256, 256, 0, stream>>>(pA3, pA3 + 256, 125, 512, g3, b3,
                                   coef + 768, coef + 1280, coef + 256, coef + 512);

    // stage 4: fused conv3+bn3 + proj+bnp + relu
    k7<<<NBLK, 256, 0, stream>>>(x, h2b, w3T, wpT, coef, out);
}

// Round 3
// 862.101 us; speedup vs baseline: 1.1373x; 1.1373x over previous
//
#include <hip/hip_runtime.h>

// ---------------------------------------------------------------------------
// ProjectionResBlock: x[N,128] -> relu(bn3(einsum(gather(relu(bn1(x@w1)))
//                      ,w2)@w3) + bnp(x@wp))
// N=200000, C_IN=128, MID=64, C_OUT=256, K=27. Output f32 [N,256].
// bf16 MFMA (16x16x32) everywhere, f32 accum. BN via partials->reduce->fold.
// k3 v2: 4 waves/block, w2 staged in double-buffered LDS (frag order) via
// global_load_lds, register prefetch of next-k gather rows.
// ---------------------------------------------------------------------------

typedef __bf16 bf16_8 __attribute__((ext_vector_type(8)));
typedef float f32x4 __attribute__((ext_vector_type(4)));

#define NN 200000
#define NBLK 3125          // N / 64

// ---- workspace byte offsets (16B-aligned) ----
#define OFF_W1T   (size_t)0               // bf16 [64][128]     16384
#define OFF_WPT   (size_t)16384           // bf16 [256][128]    65536
#define OFF_W2S   (size_t)81920           // bf16 [27][8][64][8] 221184 (frag order)
#define OFF_W3T   (size_t)303104          // bf16 [256][64]     32768
#define OFF_Y1    (size_t)335872          // bf16 [N][64]       25600000 (aliased by P3)
#define OFF_H1    (size_t)25935872        // bf16 [N][64]
#define OFF_H2B   (size_t)51535872        // bf16 [N][64]
#define OFF_P1    (size_t)77135872        // f32 [12500][640]   32000000 (aliased by Y2)
#define OFF_P2    (size_t)109135872       // f32 [12500][128]   6400000
#define OFF_COEF  (size_t)115535872       // f32 [1536]
#define OFF_PA1   (size_t)115542016       // f32 [125][640]
#define OFF_PA2   (size_t)115862016       // f32 [125][128]
#define OFF_PA3   (size_t)115926016       // f32 [125][512]
#define OFF_Y2    OFF_P1                  // bf16 [N][64] (after P1 dead)
#define OFF_P3    OFF_Y1                  // f32 [12500][512] (after Y1 dead)

// coef float indices: s1=0, t1=64, s2=128, t2=192, sp=256, tp=512,
//                     cr(=s3/sp)=768, cb(=t3+tp)=1280

// ---------------------------------------------------------------------------
// K0: weights -> bf16; w1/w3/wp transposed, w2 packed in MFMA-frag order:
//     w2S[((k*8 + nt*2 + ks)*64 + lane)*8 + j] = w2[k][ks*32+(lane>>4)*8+j][nt*16+(lane&15)]
// ---------------------------------------------------------------------------
__global__ void k_prep(const float* __restrict__ w1, const float* __restrict__ w2,
                       const float* __restrict__ w3, const float* __restrict__ wp,
                       __bf16* __restrict__ w1T, __bf16* __restrict__ w2S,
                       __bf16* __restrict__ w3T, __bf16* __restrict__ wpT) {
    int i = blockIdx.x * 256 + threadIdx.x;
    if (i < 128 * 64)  { int r = i / 64,  c = i % 64;  w1T[c * 128 + r] = (__bf16)w1[i]; }
    if (i < 27 * 64 * 64) {
        int j = i & 7, ln = (i >> 3) & 63, ks = (i >> 9) & 1, nt = (i >> 10) & 3, k = i >> 12;
        int c = ks * 32 + (ln >> 4) * 8 + j;
        int o = nt * 16 + (ln & 15);
        w2S[i] = (__bf16)w2[(k * 64 + c) * 64 + o];
    }
    if (i < 64 * 256)  { int r = i / 256, c = i % 256; w3T[c * 64 + r]  = (__bf16)w3[i]; }
    if (i < 128 * 256) { int r = i / 256, c = i % 256; wpT[c * 128 + r] = (__bf16)wp[i]; }
}

// ---------------------------------------------------------------------------
// K1: y1 = x @ w1 (store bf16) ; column sums/sumsq for [w1|wp] (320 cols)
// ---------------------------------------------------------------------------
__global__ __launch_bounds__(256) void k1(const float* __restrict__ x,
                                          const __bf16* __restrict__ w1T,
                                          const __bf16* __restrict__ wpT,
                                          __bf16* __restrict__ y1,
                                          float* __restrict__ p1) {
    int blk = blockIdx.x;
    int wave = threadIdx.x >> 6, lane = threadIdx.x & 63;
    int l15 = lane & 15, lg = lane >> 4;
    int row = blk * 64 + wave * 16 + l15;

    const float* xr = x + (size_t)row * 128 + lg * 8;
    bf16_8 a[4];
#pragma unroll
    for (int ks = 0; ks < 4; ks++) {
        float4 f0 = *(const float4*)(xr + ks * 32);
        float4 f1 = *(const float4*)(xr + ks * 32 + 4);
        bf16_8 t;
        t[0] = (__bf16)f0.x; t[1] = (__bf16)f0.y; t[2] = (__bf16)f0.z; t[3] = (__bf16)f0.w;
        t[4] = (__bf16)f1.x; t[5] = (__bf16)f1.y; t[6] = (__bf16)f1.z; t[7] = (__bf16)f1.w;
        a[ks] = t;
    }

    f32x4 acc[20];
#pragma unroll
    for (int nt = 0; nt < 20; nt++) acc[nt] = (f32x4){0.f, 0.f, 0.f, 0.f};

#pragma unroll
    for (int nt = 0; nt < 20; nt++) {
        const __bf16* bt = (nt < 4)
            ? (w1T + (size_t)(nt * 16 + l15) * 128)
            : (wpT + (size_t)((nt - 4) * 16 + l15) * 128);
#pragma unroll
        for (int ks = 0; ks < 4; ks++) {
            bf16_8 b = *(const bf16_8*)(bt + ks * 32 + lg * 8);
            acc[nt] = __builtin_amdgcn_mfma_f32_16x16x32_bf16(a[ks], b, acc[nt], 0, 0, 0);
        }
    }

#pragma unroll
    for (int nt = 0; nt < 4; nt++) {
#pragma unroll
        for (int r4 = 0; r4 < 4; r4++) {
            int gr = blk * 64 + wave * 16 + lg * 4 + r4;
            y1[(size_t)gr * 64 + nt * 16 + l15] = (__bf16)acc[nt][r4];
        }
    }

    float* prow = p1 + ((size_t)blk * 4 + wave) * 640;
#pragma unroll
    for (int nt = 0; nt < 20; nt++) {
        float s = 0.f, q = 0.f;
#pragma unroll
        for (int r4 = 0; r4 < 4; r4++) { float v = acc[nt][r4]; s += v; q += v * v; }
        s += __shfl_xor(s, 16); s += __shfl_xor(s, 32);
        q += __shfl_xor(q, 16); q += __shfl_xor(q, 32);
        if (lane < 16) { prow[nt * 16 + l15] = s; prow[320 + nt * 16 + l15] = q; }
    }
}

// ---------------------------------------------------------------------------
__global__ void k_red(const float* __restrict__ part, float* __restrict__ outp,
                      int nrows, int chunk) {
    int width = blockDim.x;
    int b = blockIdx.x, t = threadIdx.x;
    int r0 = b * chunk, r1 = r0 + chunk;
    if (r1 > nrows) r1 = nrows;
    float s = 0.f;
    for (int r = r0; r < r1; r++) s += part[(size_t)r * width + t];
    outp[(size_t)b * width + t] = s;
}

// ---------------------------------------------------------------------------
__global__ void k_fin(const float* __restrict__ psum, const float* __restrict__ psq,
                      int nrows, int rowstride,
                      const float* __restrict__ g, const float* __restrict__ b,
                      float* __restrict__ s_out, float* __restrict__ t_out,
                      const float* __restrict__ fsp, const float* __restrict__ ftp) {
    int c = blockIdx.x;
    float s = 0.f, q = 0.f;
    for (int r = threadIdx.x; r < nrows; r += blockDim.x) {
        size_t o = (size_t)r * rowstride + c;
        s += psum[o]; q += psq[o];
    }
#pragma unroll
    for (int off = 32; off; off >>= 1) { s += __shfl_xor(s, off); q += __shfl_xor(q, off); }
    __shared__ float ls[4], lq[4];
    int wv = threadIdx.x >> 6;
    if ((threadIdx.x & 63) == 0) { ls[wv] = s; lq[wv] = q; }
    __syncthreads();
    if (threadIdx.x == 0) {
        s = ls[0] + ls[1] + ls[2] + ls[3];
        q = lq[0] + lq[1] + lq[2] + lq[3];
        float m = s * (1.f / (float)NN);
        float v = q * (1.f / (float)NN) - m * m;
        float rs = rsqrtf(v + 1e-3f);
        float sc = g[c] * rs;
        float tb = b[c] - m * sc;
        if (fsp) { sc = sc / fsp[c]; tb = tb + ftp[c]; }
        s_out[c] = sc; t_out[c] = tb;
    }
}

// ---------------------------------------------------------------------------
__global__ __launch_bounds__(256) void k_h1(const __bf16* __restrict__ y1,
                                            const float* __restrict__ coef,
                                            __bf16* __restrict__ h1) {
    int i = blockIdx.x * 256 + threadIdx.x;
    int c0 = (i * 8) & 63;
    bf16_8 v = *(const bf16_8*)(y1 + (size_t)i * 8);
    bf16_8 o;
#pragma unroll
    for (int j = 0; j < 8; j++) {
        float f = (float)v[j] * coef[c0 + j] + coef[64 + c0 + j];
        o[j] = (__bf16)fmaxf(f, 0.f);
    }
    *(bf16_8*)(h1 + (size_t)i * 8) = o;
}

// ---------------------------------------------------------------------------
// K3 v2: y2[n,o] = sum_k sum_c h1[neigh[n,k],c] * w2[k,c,o]
// 256 threads = 4 waves x 16 rows. w2 double-buffered in LDS (frag order),
// staged with global_load_lds; next-k gather rows prefetched into registers.
// ---------------------------------------------------------------------------
__global__ __launch_bounds__(256) void k3(const int* __restrict__ neigh,
                                          const __bf16* __restrict__ h1,
                                          const __bf16* __restrict__ w2S,
                                          __bf16* __restrict__ y2,
                                          float* __restrict__ p2) {
    __shared__ int nl[64 * 27];            // 6912 B
    __shared__ __bf16 bs[2][4096];         // 2 x 8 KiB

    int blk = blockIdx.x, tid = threadIdx.x;
    int wave = tid >> 6, lane = tid & 63, l15 = lane & 15, lg = lane >> 4;

    for (int i = tid; i < 64 * 27; i += 256) nl[i] = neigh[(size_t)blk * (64 * 27) + i];

    // stage k=0 B-slice into bs[0]: 8192 B = 2 rounds x 256 lanes x 16 B
#pragma unroll
    for (int r = 0; r < 2; r++) {
        const char* g = (const char*)w2S + r * 4096 + wave * 1024 + lane * 16;
        char* l = (char*)&bs[0][0] + r * 4096 + wave * 1024;
        __builtin_amdgcn_global_load_lds(
            (const __attribute__((address_space(1))) unsigned int*)g,
            (__attribute__((address_space(3))) unsigned int*)l, 16, 0, 0);
    }
    __syncthreads();   // nl ready + bs[0] staged (vmcnt drained)

    int row = wave * 16 + l15;
    int idx0 = nl[row * 27 + 0];
    const __bf16* hp0 = h1 + (size_t)idx0 * 64 + lg * 8;
    bf16_8 a0 = *(const bf16_8*)(hp0);
    bf16_8 a1 = *(const bf16_8*)(hp0 + 32);

    f32x4 acc[4];
#pragma unroll
    for (int nt = 0; nt < 4; nt++) acc[nt] = (f32x4){0.f, 0.f, 0.f, 0.f};

    int cur = 0;
    for (int k = 0; k < 27; k++) {
        int kn = (k + 1 < 27) ? k + 1 : 26;
        // prefetch next-k gather rows into registers
        int idxn = nl[row * 27 + kn];
        const __bf16* hpn = h1 + (size_t)idxn * 64 + lg * 8;
        bf16_8 an0 = *(const bf16_8*)(hpn);
        bf16_8 an1 = *(const bf16_8*)(hpn + 32);
        // stage next-k B slice into the other buffer
#pragma unroll
        for (int r = 0; r < 2; r++) {
            const char* g = (const char*)w2S + (size_t)kn * 8192 + r * 4096 + wave * 1024 + lane * 16;
            char* l = (char*)&bs[cur ^ 1][0] + r * 4096 + wave * 1024;
            __builtin_amdgcn_global_load_lds(
                (const __attribute__((address_space(1))) unsigned int*)g,
                (__attribute__((address_space(3))) unsigned int*)l, 16, 0, 0);
        }
        // B fragments from LDS (lane-contiguous 16B -> conflict-free b128)
        const __bf16* bb = &bs[cur][0];
#pragma unroll
        for (int nt = 0; nt < 4; nt++) {
            bf16_8 b0 = *(const bf16_8*)(bb + ((nt * 2 + 0) * 64 + lane) * 8);
            bf16_8 b1 = *(const bf16_8*)(bb + ((nt * 2 + 1) * 64 + lane) * 8);
            acc[nt] = __builtin_amdgcn_mfma_f32_16x16x32_bf16(a0, b0, acc[nt], 0, 0, 0);
            acc[nt] = __builtin_amdgcn_mfma_f32_16x16x32_bf16(a1, b1, acc[nt], 0, 0, 0);
        }
        __syncthreads();   // staging for kn complete; all reads of bs[cur] done
        a0 = an0; a1 = an1; cur ^= 1;
    }

    // store y2 (16 rows x 64 cols per wave)
#pragma unroll
    for (int nt = 0; nt < 4; nt++)
#pragma unroll
        for (int r4 = 0; r4 < 4; r4++) {
            int gr = blk * 64 + wave * 16 + lg * 4 + r4;
            y2[(size_t)gr * 64 + nt * 16 + l15] = (__bf16)acc[nt][r4];
        }

    float* prow = p2 + ((size_t)blk * 4 + wave) * 128;
#pragma unroll
    for (int nt = 0; nt < 4; nt++) {
        float s = 0.f, q = 0.f;
#pragma unroll
        for (int r4 = 0; r4 < 4; r4++) { float v = acc[nt][r4]; s += v; q += v * v; }
        s += __shfl_xor(s, 16); s += __shfl_xor(s, 32);
        q += __shfl_xor(q, 16); q += __shfl_xor(q, 32);
        if (lane < 16) { prow[nt * 16 + l15] = s; prow[64 + nt * 16 + l15] = q; }
    }
}

// ---------------------------------------------------------------------------
// K5: h2b = relu(s2*y2+t2) bf16 (stored) ; y3 = h2b @ w3 -> column partials
// ---------------------------------------------------------------------------
__global__ __launch_bounds__(256) void k5(const __bf16* __restrict__ y2,
                                          const float* __restrict__ coef,
                                          const __bf16* __restrict__ w3T,
                                          __bf16* __restrict__ h2b,
                                          float* __restrict__ p3) {
    int blk = blockIdx.x;
    int wave = threadIdx.x >> 6, lane = threadIdx.x & 63;
    int l15 = lane & 15, lg = lane >> 4;
    int row = blk * 64 + wave * 16 + l15;

    bf16_8 a[2];
#pragma unroll
    for (int ks = 0; ks < 2; ks++) {
        bf16_8 v = *(const bf16_8*)(y2 + (size_t)row * 64 + ks * 32 + lg * 8);
        bf16_8 t;
#pragma unroll
        for (int j = 0; j < 8; j++) {
            int c = ks * 32 + lg * 8 + j;
            float f = (float)v[j] * coef[128 + c] + coef[192 + c];
            t[j] = (__bf16)fmaxf(f, 0.f);
        }
        a[ks] = t;
        *(bf16_8*)(h2b + (size_t)row * 64 + ks * 32 + lg * 8) = t;
    }

    f32x4 acc[16];
#pragma unroll
    for (int nt = 0; nt < 16; nt++) acc[nt] = (f32x4){0.f, 0.f, 0.f, 0.f};

#pragma unroll
    for (int nt = 0; nt < 16; nt++) {
        const __bf16* bp = w3T + (size_t)(nt * 16 + l15) * 64 + lg * 8;
        bf16_8 b0 = *(const bf16_8*)(bp);
        bf16_8 b1 = *(const bf16_8*)(bp + 32);
        acc[nt] = __builtin_amdgcn_mfma_f32_16x16x32_bf16(a[0], b0, acc[nt], 0, 0, 0);
        acc[nt] = __builtin_amdgcn_mfma_f32_16x16x32_bf16(a[1], b1, acc[nt], 0, 0, 0);
    }

    float* prow = p3 + ((size_t)blk * 4 + wave) * 512;
#pragma unroll
    for (int nt = 0; nt < 16; nt++) {
        float s = 0.f, q = 0.f;
#pragma unroll
        for (int r4 = 0; r4 < 4; r4++) { float v = acc[nt][r4]; s += v; q += v * v; }
        s += __shfl_xor(s, 16); s += __shfl_xor(s, 32);
        q += __shfl_xor(q, 16); q += __shfl_xor(q, 32);
        if (lane < 16) { prow[nt * 16 + l15] = s; prow[256 + nt * 16 + l15] = q; }
    }
}

// ---------------------------------------------------------------------------
// K7: out = relu( s3*(h2b@w3) + t3 + sp*(x@wp) + tp )
// ---------------------------------------------------------------------------
__global__ __launch_bounds__(256) void k7(const float* __restrict__ x,
                                          const __bf16* __restrict__ h2b,
                                          const __bf16* __restrict__ w3T,
                                          const __bf16* __restrict__ wpT,
                                          const float* __restrict__ coef,
                                          float* __restrict__ out) {
    int blk = blockIdx.x;
    int wave = threadIdx.x >> 6, lane = threadIdx.x & 63;
    int l15 = lane & 15, lg = lane >> 4;
    int row = blk * 64 + wave * 16 + l15;

    bf16_8 ah[2];
    ah[0] = *(const bf16_8*)(h2b + (size_t)row * 64 + lg * 8);
    ah[1] = *(const bf16_8*)(h2b + (size_t)row * 64 + 32 + lg * 8);

    f32x4 acc[16];
#pragma unroll
    for (int nt = 0; nt < 16; nt++) acc[nt] = (f32x4){0.f, 0.f, 0.f, 0.f};

#pragma unroll
    for (int nt = 0; nt < 16; nt++) {
        const __bf16* bp = w3T + (size_t)(nt * 16 + l15) * 64 + lg * 8;
        bf16_8 b0 = *(const bf16_8*)(bp);
        bf16_8 b1 = *(const bf16_8*)(bp + 32);
        acc[nt] = __builtin_amdgcn_mfma_f32_16x16x32_bf16(ah[0], b0, acc[nt], 0, 0, 0);
        acc[nt] = __builtin_amdgcn_mfma_f32_16x16x32_bf16(ah[1], b1, acc[nt], 0, 0, 0);
    }

#pragma unroll
    for (int nt = 0; nt < 16; nt++) {
        float r = coef[768 + nt * 16 + l15];
        acc[nt] *= r;
    }

    const float* xr = x + (size_t)row * 128 + lg * 8;
    bf16_8 ax[4];
#pragma unroll
    for (int ks = 0; ks < 4; ks++) {
        float4 f0 = *(const float4*)(xr + ks * 32);
        float4 f1 = *(const float4*)(xr + ks * 32 + 4);
        bf16_8 t;
        t[0] = (__bf16)f0.x; t[1] = (__bf16)f0.y; t[2] = (__bf16)f0.z; t[3] = (__bf16)f0.w;
        t[4] = (__bf16)f1.x; t[5] = (__bf16)f1.y; t[6] = (__bf16)f1.z; t[7] = (__bf16)f1.w;
        ax[ks] = t;
    }
#pragma unroll
    for (int nt = 0; nt < 16; nt++) {
        const __bf16* bp = wpT + (size_t)(nt * 16 + l15) * 128 + lg * 8;
#pragma unroll
        for (int ks = 0; ks < 4; ks++) {
            bf16_8 b = *(const bf16_8*)(bp + ks * 32);
            acc[nt] = __builtin_amdgcn_mfma_f32_16x16x32_bf16(ax[ks], b, acc[nt], 0, 0, 0);
        }
    }

#pragma unroll
    for (int nt = 0; nt < 16; nt++) {
        int c = nt * 16 + l15;
        float cs = coef[256 + c];
        float cb = coef[1280 + c];
#pragma unroll
        for (int r4 = 0; r4 < 4; r4++) {
            int gr = blk * 64 + wave * 16 + lg * 4 + r4;
            out[(size_t)gr * 256 + c] = fmaxf(acc[nt][r4] * cs + cb, 0.f);
        }
    }
}

// ---------------------------------------------------------------------------
extern "C" void kernel_launch(void* const* d_in, const int* in_sizes, int n_in,
                              void* d_out, int out_size, void* d_ws, size_t ws_size,
                              hipStream_t stream) {
    const float* x     = (const float*)d_in[0];
    const int*   neigh = (const int*)d_in[1];
    const float* w1 = (const float*)d_in[3];
    const float* g1 = (const float*)d_in[4];
    const float* b1 = (const float*)d_in[5];
    const float* w2 = (const float*)d_in[6];
    const float* g2 = (const float*)d_in[7];
    const float* b2 = (const float*)d_in[8];
    const float* w3 = (const float*)d_in[9];
    const float* g3 = (const float*)d_in[10];
    const float* b3 = (const float*)d_in[11];
    const float* wp = (const float*)d_in[12];
    const float* gp = (const float*)d_in[13];
    const float* bp = (const float*)d_in[14];
    float* out = (float*)d_out;

    char* ws = (char*)d_ws;
    __bf16* w1T = (__bf16*)(ws + OFF_W1T);
    __bf16* wpT = (__bf16*)(ws + OFF_WPT);
    __bf16* w2S = (__bf16*)(ws + OFF_W2S);
    __bf16* w3T = (__bf16*)(ws + OFF_W3T);
    __bf16* y1  = (__bf16*)(ws + OFF_Y1);
    __bf16* h1  = (__bf16*)(ws + OFF_H1);
    __bf16* y2  = (__bf16*)(ws + OFF_Y2);
    __bf16* h2b = (__bf16*)(ws + OFF_H2B);
    float* p1   = (float*)(ws + OFF_P1);
    float* p2   = (float*)(ws + OFF_P2);
    float* p3   = (float*)(ws + OFF_P3);
    float* coef = (float*)(ws + OFF_COEF);
    float* pA1  = (float*)(ws + OFF_PA1);
    float* pA2  = (float*)(ws + OFF_PA2);
    float* pA3  = (float*)(ws + OFF_PA3);

    // stage 0: weights -> bf16 (w2 in MFMA-frag order)
    k_prep<<<432, 256, 0, stream>>>(w1, w2, w3, wp, w1T, w2S, w3T, wpT);

    // stage 1: y1 = x@w1 (+ stats for w1 and wp branches)
    k1<<<NBLK, 256, 0, stream>>>(x, w1T, wpT, y1, p1);
    k_red<<<125, 640, 0, stream>>>(p1, pA1, 12500, 100);
    k_fin<<<64, 256, 0, stream>>>(pA1, pA1 + 320, 125, 640, g1, b1,
                                  coef + 0, coef + 64, nullptr, nullptr);
    k_fin<<<256, 256, 0, stream>>>(pA1 + 64, pA1 + 384, 125, 640, gp, bp,
                                   coef + 256, coef + 512, nullptr, nullptr);

    // stage 1b: h1 = relu(bn1(y1))   (y1 dead after this -> P3 may alias)
    k_h1<<<6250, 256, 0, stream>>>(y1, coef, h1);

    // stage 2: gather einsum (writes y2 into former P1 region)
    k3<<<NBLK, 256, 0, stream>>>(neigh, h1, w2S, y2, p2);
    k_red<<<125, 128, 0, stream>>>(p2, pA2, 12500, 100);
    k_fin<<<64, 256, 0, stream>>>(pA2, pA2 + 64, 125, 128, g2, b2,
                                  coef + 128, coef + 192, nullptr, nullptr);

    // stage 3: h2b = relu(bn2(y2)); y3 stats
    k5<<<NBLK, 256, 0, stream>>>(y2, coef, w3T, h2b, p3);
    k_red<<<125, 512, 0, stream>>>(p3, pA3, 12500, 100);
    k_fin<<<256, 256, 0, stream>>>(pA3, pA3 + 256, 125, 512, g3, b3,
                                   coef + 768, coef + 1280, coef + 256, coef + 512);

    // stage 4: fused conv3+bn3 + proj+bnp + relu
    k7<<<NBLK, 256, 0, stream>>>(x, h2b, w3T, wpT, coef, out);
}

// Round 4
// 619.756 us; speedup vs baseline: 1.5820x; 1.3910x over previous
//
#include <hip/hip_runtime.h>

// ---------------------------------------------------------------------------
// ProjectionResBlock: x[N,128] -> relu(bn3(einsum(gather(relu(bn1(x@w1))),w2)@w3) + bnp(x@wp))
// N=200000, C_IN=128, MID=64, C_OUT=256, K=27. Output f32 [N,256].
// bf16 MFMA 16x16x32, f32 accum. BN via partials->reduce->fold into scale/bias.
// v3: k1/k7 stage fragment-packed B in LDS (global_load_lds) + coalesced
// LDS-transpose epilogues; k3 folds BN1+relu into the gather (k_h1 deleted).
// ---------------------------------------------------------------------------

typedef __bf16 bf16_8 __attribute__((ext_vector_type(8)));
typedef float f32x4 __attribute__((ext_vector_type(4)));

#define NN 200000
#define NBLK 3125          // N / 64

// ---- workspace byte offsets (16B-aligned) ----
#define OFF_WA    (size_t)0               // bf16 [20][4][64][8]  81920  (w1|wp frag-packed, K=128)
#define OFF_W3S   (size_t)81920           // bf16 [16][2][64][8]  32768  (w3 frag-packed, K=64)
#define OFF_W2S   (size_t)114688          // bf16 [27][4][2][64][8] 221184
#define OFF_Y1    (size_t)335872          // bf16 [N][64]  25600000
#define OFF_P1    (size_t)25935872        // f32 [12500][640] 32000000
#define OFF_P2    (size_t)57935872        // f32 [12500][128] 6400000
#define OFF_Y2    (size_t)64335872        // bf16 [N][64]  25600000
#define OFF_H2B   (size_t)89935872        // bf16 [N][64]  25600000
#define OFF_P3    (size_t)115535872       // f32 [12500][512] 25600000
#define OFF_COEF  (size_t)141135872       // f32 [1536]
#define OFF_PA1   (size_t)141142016       // f32 [125][640]
#define OFF_PA2   (size_t)141462016       // f32 [125][128]
#define OFF_PA3   (size_t)141526016       // f32 [125][512]
// total ~141.8 MB

// coef float indices: s1=0, t1=64, s2=128, t2=192, sp=256, tp=512,
//                     cr(=s3/sp)=768, cb(=t3+tp)=1280

#define GLDS(gptr, lptr) __builtin_amdgcn_global_load_lds( \
    (const __attribute__((address_space(1))) unsigned int*)(gptr), \
    (__attribute__((address_space(3))) unsigned int*)(lptr), 16, 0, 0)

// ---------------------------------------------------------------------------
// K0: weights -> bf16 fragment-packed.
// wA[((nt*4+ks)*64+ln)*8+j]: nt<4 -> w1[K=ks*32+(ln>>4)*8+j][nt*16+(ln&15)]
//                            nt>=4 -> wp[same K][(nt-4)*16+(ln&15)]
// w3S[((nt*2+ks)*64+ln)*8+j] = w3[ks*32+(ln>>4)*8+j][nt*16+(ln&15)]
// w2S[(((k*4+nt)*2+ks)*64+ln)*8+j] = w2[k][ks*32+(ln>>4)*8+j][nt*16+(ln&15)]
// ---------------------------------------------------------------------------
__global__ void k_prep(const float* __restrict__ w1, const float* __restrict__ w2,
                       const float* __restrict__ w3, const float* __restrict__ wp,
                       __bf16* __restrict__ wA, __bf16* __restrict__ w2S,
                       __bf16* __restrict__ w3S) {
    int i = blockIdx.x * 256 + threadIdx.x;
    if (i < 40960) {
        int j = i & 7, ln = (i >> 3) & 63, ks = (i >> 9) & 3, nt = i >> 11;
        int r = ks * 32 + (ln >> 4) * 8 + j;
        if (nt < 4) wA[i] = (__bf16)w1[r * 64 + nt * 16 + (ln & 15)];
        else        wA[i] = (__bf16)wp[r * 256 + (nt - 4) * 16 + (ln & 15)];
    }
    if (i < 16384) {
        int j = i & 7, ln = (i >> 3) & 63, ks = (i >> 9) & 1, nt = i >> 10;
        int r = ks * 32 + (ln >> 4) * 8 + j;
        w3S[i] = (__bf16)w3[r * 256 + nt * 16 + (ln & 15)];
    }
    if (i < 110592) {
        int j = i & 7, ln = (i >> 3) & 63, ks = (i >> 9) & 1, nt = (i >> 10) & 3, k = i >> 12;
        int c = ks * 32 + (ln >> 4) * 8 + j;
        int o = nt * 16 + (ln & 15);
        w2S[i] = (__bf16)w2[(k * 64 + c) * 64 + o];
    }
}

// ---------------------------------------------------------------------------
// K1: y1 = x @ w1 (bf16, coalesced via LDS transpose); col partials for
// [w1|wp] (320 cols). B (wA, 80KB) staged in LDS in two 40KB halves.
// ---------------------------------------------------------------------------
__global__ __launch_bounds__(256) void k1(const float* __restrict__ x,
                                          const __bf16* __restrict__ wA,
                                          __bf16* __restrict__ y1,
                                          float* __restrict__ p1) {
    __shared__ __align__(16) __bf16 bs[20480];     // 40 KB B half
    __shared__ __align__(16) __bf16 yl[64][72];    // 9 KB y1 transpose tile
    int blk = blockIdx.x, tid = threadIdx.x;
    int wave = tid >> 6, lane = tid & 63, l15 = lane & 15, lg = lane >> 4;

    // stage half 0 (nt 0..9)
#pragma unroll
    for (int r = 0; r < 10; r++) {
        const char* g = (const char*)wA + r * 4096 + wave * 1024 + lane * 16;
        char* l = (char*)bs + r * 4096 + wave * 1024;
        GLDS(g, l);
    }

    int row = blk * 64 + wave * 16 + l15;
    const float* xr = x + (size_t)row * 128 + lg * 8;
    bf16_8 a[4];
#pragma unroll
    for (int ks = 0; ks < 4; ks++) {
        float4 f0 = *(const float4*)(xr + ks * 32);
        float4 f1 = *(const float4*)(xr + ks * 32 + 4);
        bf16_8 t;
        t[0] = (__bf16)f0.x; t[1] = (__bf16)f0.y; t[2] = (__bf16)f0.z; t[3] = (__bf16)f0.w;
        t[4] = (__bf16)f1.x; t[5] = (__bf16)f1.y; t[6] = (__bf16)f1.z; t[7] = (__bf16)f1.w;
        a[ks] = t;
    }

    f32x4 acc[20];
#pragma unroll
    for (int nt = 0; nt < 20; nt++) acc[nt] = (f32x4){0.f, 0.f, 0.f, 0.f};

    __syncthreads();   // half0 staged
#pragma unroll
    for (int nt = 0; nt < 10; nt++) {
#pragma unroll
        for (int ks = 0; ks < 4; ks++) {
            bf16_8 b = *(const bf16_8*)(bs + ((nt * 4 + ks) * 64 + lane) * 8);
            acc[nt] = __builtin_amdgcn_mfma_f32_16x16x32_bf16(a[ks], b, acc[nt], 0, 0, 0);
        }
    }
    __syncthreads();   // done reading half0

    // stage half 1 (nt 10..19)
#pragma unroll
    for (int r = 0; r < 10; r++) {
        const char* g = (const char*)wA + 40960 + r * 4096 + wave * 1024 + lane * 16;
        char* l = (char*)bs + r * 4096 + wave * 1024;
        GLDS(g, l);
    }
    // y1 tile (nt 0..3 ready)
#pragma unroll
    for (int nt = 0; nt < 4; nt++)
#pragma unroll
        for (int r4 = 0; r4 < 4; r4++)
            yl[wave * 16 + lg * 4 + r4][nt * 16 + l15] = (__bf16)acc[nt][r4];
    __syncthreads();   // half1 staged + yl visible

    // coalesced y1 store: 2 passes x (32 rows x 128 B)
#pragma unroll
    for (int p = 0; p < 2; p++) {
        int rr = p * 32 + (tid >> 3), c8 = tid & 7;
        bf16_8 v = *(const bf16_8*)&yl[rr][c8 * 8];
        *(bf16_8*)(y1 + (size_t)(blk * 64 + rr) * 64 + c8 * 8) = v;
    }

#pragma unroll
    for (int nt = 10; nt < 20; nt++) {
#pragma unroll
        for (int ks = 0; ks < 4; ks++) {
            bf16_8 b = *(const bf16_8*)(bs + (((nt - 10) * 4 + ks) * 64 + lane) * 8);
            acc[nt] = __builtin_amdgcn_mfma_f32_16x16x32_bf16(a[ks], b, acc[nt], 0, 0, 0);
        }
    }

    float* prow = p1 + ((size_t)blk * 4 + wave) * 640;
#pragma unroll
    for (int nt = 0; nt < 20; nt++) {
        float s = 0.f, q = 0.f;
#pragma unroll
        for (int r4 = 0; r4 < 4; r4++) { float v = acc[nt][r4]; s += v; q += v * v; }
        s += __shfl_xor(s, 16); s += __shfl_xor(s, 32);
        q += __shfl_xor(q, 16); q += __shfl_xor(q, 32);
        if (lane < 16) { prow[nt * 16 + l15] = s; prow[320 + nt * 16 + l15] = q; }
    }
}

// ---------------------------------------------------------------------------
__global__ void k_red(const float* __restrict__ part, float* __restrict__ outp,
                      int nrows, int chunk) {
    int width = blockDim.x;
    int b = blockIdx.x, t = threadIdx.x;
    int r0 = b * chunk, r1 = r0 + chunk;
    if (r1 > nrows) r1 = nrows;
    float s = 0.f;
    for (int r = r0; r < r1; r++) s += part[(size_t)r * width + t];
    outp[(size_t)b * width + t] = s;
}

// ---------------------------------------------------------------------------
__global__ void k_fin(const float* __restrict__ psum, const float* __restrict__ psq,
                      int nrows, int rowstride,
                      const float* __restrict__ g, const float* __restrict__ b,
                      float* __restrict__ s_out, float* __restrict__ t_out,
                      const float* __restrict__ fsp, const float* __restrict__ ftp) {
    int c = blockIdx.x;
    float s = 0.f, q = 0.f;
    for (int r = threadIdx.x; r < nrows; r += blockDim.x) {
        size_t o = (size_t)r * rowstride + c;
        s += psum[o]; q += psq[o];
    }
#pragma unroll
    for (int off = 32; off; off >>= 1) { s += __shfl_xor(s, off); q += __shfl_xor(q, off); }
    __shared__ float ls[4], lq[4];
    int wv = threadIdx.x >> 6;
    if ((threadIdx.x & 63) == 0) { ls[wv] = s; lq[wv] = q; }
    __syncthreads();
    if (threadIdx.x == 0) {
        s = ls[0] + ls[1] + ls[2] + ls[3];
        q = lq[0] + lq[1] + lq[2] + lq[3];
        float m = s * (1.f / (float)NN);
        float v = q * (1.f / (float)NN) - m * m;
        float rs = rsqrtf(v + 1e-3f);
        float sc = g[c] * rs;
        float tb = b[c] - m * sc;
        if (fsp) { sc = sc / fsp[c]; tb = tb + ftp[c]; }
        s_out[c] = sc; t_out[c] = tb;
    }
}

// ---------------------------------------------------------------------------
// K3 v3: y2 = einsum(gather(relu(bn1(y1))), w2); BN1+relu applied on the fly.
// 4 waves x 16 rows; w2 double-buffered in LDS; next-k rows prefetched.
// ---------------------------------------------------------------------------
__global__ __launch_bounds__(256) void k3(const int* __restrict__ neigh,
                                          const __bf16* __restrict__ y1,
                                          const __bf16* __restrict__ w2S,
                                          const float* __restrict__ coef,
                                          __bf16* __restrict__ y2,
                                          float* __restrict__ p2) {
    __shared__ int nl[64 * 27];
    __shared__ __align__(16) __bf16 bsb[2][4096];

    int blk = blockIdx.x, tid = threadIdx.x;
    int wave = tid >> 6, lane = tid & 63, l15 = lane & 15, lg = lane >> 4;

    for (int i = tid; i < 64 * 27; i += 256) nl[i] = neigh[(size_t)blk * (64 * 27) + i];

    // per-lane BN1 scale/bias for the 16 K-elements this lane holds
    float s0[8], t0[8], s1c[8], t1c[8];
#pragma unroll
    for (int j = 0; j < 8; j++) {
        int c = lg * 8 + j;
        s0[j]  = coef[c];       t0[j]  = coef[64 + c];
        s1c[j] = coef[32 + c];  t1c[j] = coef[96 + c];
    }

#pragma unroll
    for (int r = 0; r < 2; r++) {
        const char* g = (const char*)w2S + r * 4096 + wave * 1024 + lane * 16;
        char* l = (char*)&bsb[0][0] + r * 4096 + wave * 1024;
        GLDS(g, l);
    }
    __syncthreads();

    int row27 = (wave * 16 + l15) * 27;
    int idx0 = nl[row27];
    const __bf16* hp0 = y1 + (size_t)idx0 * 64 + lg * 8;
    bf16_8 r0 = *(const bf16_8*)(hp0);
    bf16_8 r1 = *(const bf16_8*)(hp0 + 32);
    bf16_8 a0, a1;
#pragma unroll
    for (int j = 0; j < 8; j++) {
        a0[j] = (__bf16)fmaxf((float)r0[j] * s0[j] + t0[j], 0.f);
        a1[j] = (__bf16)fmaxf((float)r1[j] * s1c[j] + t1c[j], 0.f);
    }

    f32x4 acc[4];
#pragma unroll
    for (int nt = 0; nt < 4; nt++) acc[nt] = (f32x4){0.f, 0.f, 0.f, 0.f};

    int cur = 0;
    for (int k = 0; k < 27; k++) {
        int kn = (k + 1 < 27) ? k + 1 : 26;
        int idxn = nl[row27 + kn];
        const __bf16* hpn = y1 + (size_t)idxn * 64 + lg * 8;
        bf16_8 rn0 = *(const bf16_8*)(hpn);
        bf16_8 rn1 = *(const bf16_8*)(hpn + 32);
#pragma unroll
        for (int r = 0; r < 2; r++) {
            const char* g = (const char*)w2S + (size_t)kn * 8192 + r * 4096 + wave * 1024 + lane * 16;
            char* l = (char*)&bsb[cur ^ 1][0] + r * 4096 + wave * 1024;
            GLDS(g, l);
        }
        const __bf16* bb = &bsb[cur][0];
#pragma unroll
        for (int nt = 0; nt < 4; nt++) {
            bf16_8 b0 = *(const bf16_8*)(bb + ((nt * 2 + 0) * 64 + lane) * 8);
            bf16_8 b1 = *(const bf16_8*)(bb + ((nt * 2 + 1) * 64 + lane) * 8);
            acc[nt] = __builtin_amdgcn_mfma_f32_16x16x32_bf16(a0, b0, acc[nt], 0, 0, 0);
            acc[nt] = __builtin_amdgcn_mfma_f32_16x16x32_bf16(a1, b1, acc[nt], 0, 0, 0);
        }
        __syncthreads();
#pragma unroll
        for (int j = 0; j < 8; j++) {
            a0[j] = (__bf16)fmaxf((float)rn0[j] * s0[j] + t0[j], 0.f);
            a1[j] = (__bf16)fmaxf((float)rn1[j] * s1c[j] + t1c[j], 0.f);
        }
        cur ^= 1;
    }

#pragma unroll
    for (int nt = 0; nt < 4; nt++)
#pragma unroll
        for (int r4 = 0; r4 < 4; r4++) {
            int gr = blk * 64 + wave * 16 + lg * 4 + r4;
            y2[(size_t)gr * 64 + nt * 16 + l15] = (__bf16)acc[nt][r4];
        }

    float* prow = p2 + ((size_t)blk * 4 + wave) * 128;
#pragma unroll
    for (int nt = 0; nt < 4; nt++) {
        float s = 0.f, q = 0.f;
#pragma unroll
        for (int r4 = 0; r4 < 4; r4++) { float v = acc[nt][r4]; s += v; q += v * v; }
        s += __shfl_xor(s, 16); s += __shfl_xor(s, 32);
        q += __shfl_xor(q, 16); q += __shfl_xor(q, 32);
        if (lane < 16) { prow[nt * 16 + l15] = s; prow[64 + nt * 16 + l15] = q; }
    }
}

// ---------------------------------------------------------------------------
// K5: h2b = relu(s2*y2+t2) bf16 (stored); y3 = h2b @ w3 -> column partials
// ---------------------------------------------------------------------------
__global__ __launch_bounds__(256) void k5(const __bf16* __restrict__ y2,
                                          const float* __restrict__ coef,
                                          const __bf16* __restrict__ w3S,
                                          __bf16* __restrict__ h2b,
                                          float* __restrict__ p3) {
    int blk = blockIdx.x;
    int wave = threadIdx.x >> 6, lane = threadIdx.x & 63;
    int l15 = lane & 15, lg = lane >> 4;
    int row = blk * 64 + wave * 16 + l15;

    bf16_8 a[2];
#pragma unroll
    for (int ks = 0; ks < 2; ks++) {
        bf16_8 v = *(const bf16_8*)(y2 + (size_t)row * 64 + ks * 32 + lg * 8);
        bf16_8 t;
#pragma unroll
        for (int j = 0; j < 8; j++) {
            int c = ks * 32 + lg * 8 + j;
            float f = (float)v[j] * coef[128 + c] + coef[192 + c];
            t[j] = (__bf16)fmaxf(f, 0.f);
        }
        a[ks] = t;
        *(bf16_8*)(h2b + (size_t)row * 64 + ks * 32 + lg * 8) = t;
    }

    f32x4 acc[16];
#pragma unroll
    for (int nt = 0; nt < 16; nt++) acc[nt] = (f32x4){0.f, 0.f, 0.f, 0.f};

#pragma unroll
    for (int nt = 0; nt < 16; nt++) {
        bf16_8 b0 = *(const bf16_8*)(w3S + ((nt * 2 + 0) * 64 + lane) * 8);
        bf16_8 b1 = *(const bf16_8*)(w3S + ((nt * 2 + 1) * 64 + lane) * 8);
        acc[nt] = __builtin_amdgcn_mfma_f32_16x16x32_bf16(a[0], b0, acc[nt], 0, 0, 0);
        acc[nt] = __builtin_amdgcn_mfma_f32_16x16x32_bf16(a[1], b1, acc[nt], 0, 0, 0);
    }

    float* prow = p3 + ((size_t)blk * 4 + wave) * 512;
#pragma unroll
    for (int nt = 0; nt < 16; nt++) {
        float s = 0.f, q = 0.f;
#pragma unroll
        for (int r4 = 0; r4 < 4; r4++) { float v = acc[nt][r4]; s += v; q += v * v; }
        s += __shfl_xor(s, 16); s += __shfl_xor(s, 32);
        q += __shfl_xor(q, 16); q += __shfl_xor(q, 32);
        if (lane < 16) { prow[nt * 16 + l15] = s; prow[256 + nt * 16 + l15] = q; }
    }
}

// ---------------------------------------------------------------------------
// K7: out = relu(s3*(h2b@w3) + t3 + sp*(x@wp) + tp), via cr/cb fold.
// B staged in LDS per 128-col half; f32 LDS-transpose epilogue, dwordx4 stores.
// ---------------------------------------------------------------------------
__global__ __launch_bounds__(256) void k7(const float* __restrict__ x,
                                          const __bf16* __restrict__ h2b,
                                          const __bf16* __restrict__ w3S,
                                          const __bf16* __restrict__ wA,
                                          const float* __restrict__ coef,
                                          float* __restrict__ out) {
    __shared__ __align__(16) char smem[49152];   // 48 KB: B half / f32[64][132] epilogue
    int blk = blockIdx.x, tid = threadIdx.x;
    int wave = tid >> 6, lane = tid & 63, l15 = lane & 15, lg = lane >> 4;
    int row = blk * 64 + wave * 16 + l15;

    const __bf16* bsw3 = (const __bf16*)smem;
    const __bf16* bswp = (const __bf16*)(smem + 16384);
    float* el = (float*)smem;

    // A fragments (kept across halves)
    const __bf16* hp = h2b + (size_t)row * 64 + lg * 8;
    bf16_8 ah0 = *(const bf16_8*)hp;
    bf16_8 ah1 = *(const bf16_8*)(hp + 32);
    const float* xr = x + (size_t)row * 128 + lg * 8;
    bf16_8 ax[4];
#pragma unroll
    for (int ks = 0; ks < 4; ks++) {
        float4 f0 = *(const float4*)(xr + ks * 32);
        float4 f1 = *(const float4*)(xr + ks * 32 + 4);
        bf16_8 t;
        t[0] = (__bf16)f0.x; t[1] = (__bf16)f0.y; t[2] = (__bf16)f0.z; t[3] = (__bf16)f0.w;
        t[4] = (__bf16)f1.x; t[5] = (__bf16)f1.y; t[6] = (__bf16)f1.z; t[7] = (__bf16)f1.w;
        ax[ks] = t;
    }

#pragma unroll
    for (int h = 0; h < 2; h++) {
        // stage w3 half (16 KB) + wp half (32 KB)
#pragma unroll
        for (int r = 0; r < 4; r++) {
            const char* g = (const char*)w3S + h * 16384 + r * 4096 + wave * 1024 + lane * 16;
            char* l = smem + r * 4096 + wave * 1024;
            GLDS(g, l);
        }
#pragma unroll
        for (int r = 0; r < 8; r++) {
            const char* g = (const char*)wA + (4 + h * 8) * 4096 + r * 4096 + wave * 1024 + lane * 16;
            char* l = smem + 16384 + r * 4096 + wave * 1024;
            GLDS(g, l);
        }
        __syncthreads();   // staged (vmcnt drained)

        f32x4 acc[8];
#pragma unroll
        for (int nt = 0; nt < 8; nt++) acc[nt] = (f32x4){0.f, 0.f, 0.f, 0.f};

#pragma unroll
        for (int nt = 0; nt < 8; nt++) {
            bf16_8 b0 = *(const bf16_8*)(bsw3 + ((nt * 2 + 0) * 64 + lane) * 8);
            bf16_8 b1 = *(const bf16_8*)(bsw3 + ((nt * 2 + 1) * 64 + lane) * 8);
            acc[nt] = __builtin_amdgcn_mfma_f32_16x16x32_bf16(ah0, b0, acc[nt], 0, 0, 0);
            acc[nt] = __builtin_amdgcn_mfma_f32_16x16x32_bf16(ah1, b1, acc[nt], 0, 0, 0);
        }
#pragma unroll
        for (int nt = 0; nt < 8; nt++) acc[nt] *= coef[768 + h * 128 + nt * 16 + l15];
#pragma unroll
        for (int nt = 0; nt < 8; nt++) {
#pragma unroll
            for (int ks = 0; ks < 4; ks++) {
                bf16_8 b = *(const bf16_8*)(bswp + ((nt * 4 + ks) * 64 + lane) * 8);
                acc[nt] = __builtin_amdgcn_mfma_f32_16x16x32_bf16(ax[ks], b, acc[nt], 0, 0, 0);
            }
        }
        __syncthreads();   // done reading B half

        // epilogue: apply sp/bias+relu, transpose via LDS, dwordx4 stores
#pragma unroll
        for (int nt = 0; nt < 8; nt++) {
            int gc = h * 128 + nt * 16 + l15;
            float cs = coef[256 + gc], cb = coef[1280 + gc];
#pragma unroll
            for (int r4 = 0; r4 < 4; r4++)
                el[(wave * 16 + lg * 4 + r4) * 132 + nt * 16 + l15] =
                    fmaxf(acc[nt][r4] * cs + cb, 0.f);
        }
        __syncthreads();   // el visible
#pragma unroll
        for (int p = 0; p < 8; p++) {
            int rr = p * 8 + (tid >> 5), c4 = tid & 31;
            float4 v = *(const float4*)&el[rr * 132 + c4 * 4];
            *(float4*)(out + (size_t)(blk * 64 + rr) * 256 + h * 128 + c4 * 4) = v;
        }
        __syncthreads();   // before next half re-stages smem
    }
}

// ---------------------------------------------------------------------------
extern "C" void kernel_launch(void* const* d_in, const int* in_sizes, int n_in,
                              void* d_out, int out_size, void* d_ws, size_t ws_size,
                              hipStream_t stream) {
    const float* x     = (const float*)d_in[0];
    const int*   neigh = (const int*)d_in[1];
    const float* w1 = (const float*)d_in[3];
    const float* g1 = (const float*)d_in[4];
    const float* b1 = (const float*)d_in[5];
    const float* w2 = (const float*)d_in[6];
    const float* g2 = (const float*)d_in[7];
    const float* b2 = (const float*)d_in[8];
    const float* w3 = (const float*)d_in[9];
    const float* g3 = (const float*)d_in[10];
    const float* b3 = (const float*)d_in[11];
    const float* wp = (const float*)d_in[12];
    const float* gp = (const float*)d_in[13];
    const float* bp = (const float*)d_in[14];
    float* out = (float*)d_out;

    char* ws = (char*)d_ws;
    __bf16* wA  = (__bf16*)(ws + OFF_WA);
    __bf16* w3S = (__bf16*)(ws + OFF_W3S);
    __bf16* w2S = (__bf16*)(ws + OFF_W2S);
    __bf16* y1  = (__bf16*)(ws + OFF_Y1);
    __bf16* y2  = (__bf16*)(ws + OFF_Y2);
    __bf16* h2b = (__bf16*)(ws + OFF_H2B);
    float* p1   = (float*)(ws + OFF_P1);
    float* p2   = (float*)(ws + OFF_P2);
    float* p3   = (float*)(ws + OFF_P3);
    float* coef = (float*)(ws + OFF_COEF);
    float* pA1  = (float*)(ws + OFF_PA1);
    float* pA2  = (float*)(ws + OFF_PA2);
    float* pA3  = (float*)(ws + OFF_PA3);

    k_prep<<<432, 256, 0, stream>>>(w1, w2, w3, wp, wA, w2S, w3S);

    k1<<<NBLK, 256, 0, stream>>>(x, wA, y1, p1);
    k_red<<<125, 640, 0, stream>>>(p1, pA1, 12500, 100);
    k_fin<<<64, 256, 0, stream>>>(pA1, pA1 + 320, 125, 640, g1, b1,
                                  coef + 0, coef + 64, nullptr, nullptr);
    k_fin<<<256, 256, 0, stream>>>(pA1 + 64, pA1 + 384, 125, 640, gp, bp,
                                   coef + 256, coef + 512, nullptr, nullptr);

    k3<<<NBLK, 256, 0, stream>>>(neigh, y1, w2S, coef, y2, p2);
    k_red<<<125, 128, 0, stream>>>(p2, pA2, 12500, 100);
    k_fin<<<64, 256, 0, stream>>>(pA2, pA2 + 64, 125, 128, g2, b2,
                                  coef + 128, coef + 192, nullptr, nullptr);

    k5<<<NBLK, 256, 0, stream>>>(y2, coef, w3S, h2b, p3);
    k_red<<<125, 512, 0, stream>>>(p3, pA3, 12500, 100);
    k_fin<<<256, 256, 0, stream>>>(pA3, pA3 + 256, 125, 512, g3, b3,
                                   coef + 768, coef + 1280, coef + 256, coef + 512);

    k7<<<NBLK, 256, 0, stream>>>(x, h2b, w3S, wA, coef, out);
}

// Round 5
// 588.417 us; speedup vs baseline: 1.6663x; 1.0533x over previous
//
#include <hip/hip_runtime.h>

// ---------------------------------------------------------------------------
// ProjectionResBlock: x[N,128] -> relu(bn3(einsum(gather(relu(bn1(x@w1))),w2)@w3) + bnp(x@wp))
// N=200000, C_IN=128, MID=64, C_OUT=256, K=27. Output f32 [N,256].
// bf16 MFMA 16x16x32, f32 accum. BN via partials->reduce->fold into scale/bias.
// v4: BN1 unfolded from k3 (k_h1 pass, gather loop is pure MFMA+loads, depth-2
// prefetch). k5 GEMM eliminated: bn3 stats via colsum + M = h2b^T h2b
// (MFMA, 64x64), finalized analytically; k7 recomputes h2b from y2.
// ---------------------------------------------------------------------------

typedef __bf16 bf16_8 __attribute__((ext_vector_type(8)));
typedef float f32x4 __attribute__((ext_vector_type(4)));

#define NN 200000
#define NBLK 3125          // N / 64

// ---- workspace byte offsets (16B-aligned) ----
#define OFF_WA    (size_t)0               // bf16 [20][4][64][8]  81920 (w1|wp frag-packed)
#define OFF_W3S   (size_t)81920           // bf16 [16][2][64][8]  32768 (w3 frag-packed)
#define OFF_W2S   (size_t)114688          // bf16 [27][4][2][64][8] 221184
#define OFF_Y1    (size_t)335872          // bf16 [N][64]  25600000
#define OFF_P1    (size_t)25935872        // f32 [12500][640] 32000000
#define OFF_P2    (size_t)57935872        // f32 [12500][128] 6400000
#define OFF_Y2    (size_t)64335872        // bf16 [N][64]  25600000
#define OFF_H1    (size_t)89935872        // bf16 [N][64]  25600000
#define OFF_COEF  (size_t)115535872       // f32 [1536]
#define OFF_PA1   (size_t)115542016       // f32 [125][640]
#define OFF_PA2   (size_t)115862016       // f32 [125][128]
#define OFF_MP    (size_t)115926016       // f32 [512][64][64] 8388608
#define OFF_CSP   (size_t)124314624       // f32 [512][64]     131072
#define OFF_MM    (size_t)124445696       // f32 [64][64]      16384
#define OFF_CS    (size_t)124462080       // f32 [64]          256
// total ~124.5 MB

// coef float indices: s1=0, t1=64, s2=128, t2=192, sp=256, tp=512,
//                     cr(=s3/sp)=768, cb(=t3+tp)=1280

#define GLDS(gptr, lptr) __builtin_amdgcn_global_load_lds( \
    (const __attribute__((address_space(1))) unsigned int*)(gptr), \
    (__attribute__((address_space(3))) unsigned int*)(lptr), 16, 0, 0)

// ---------------------------------------------------------------------------
// K0: weights -> bf16 fragment-packed (see v3 comments).
// ---------------------------------------------------------------------------
__global__ void k_prep(const float* __restrict__ w1, const float* __restrict__ w2,
                       const float* __restrict__ w3, const float* __restrict__ wp,
                       __bf16* __restrict__ wA, __bf16* __restrict__ w2S,
                       __bf16* __restrict__ w3S) {
    int i = blockIdx.x * 256 + threadIdx.x;
    if (i < 40960) {
        int j = i & 7, ln = (i >> 3) & 63, ks = (i >> 9) & 3, nt = i >> 11;
        int r = ks * 32 + (ln >> 4) * 8 + j;
        if (nt < 4) wA[i] = (__bf16)w1[r * 64 + nt * 16 + (ln & 15)];
        else        wA[i] = (__bf16)wp[r * 256 + (nt - 4) * 16 + (ln & 15)];
    }
    if (i < 16384) {
        int j = i & 7, ln = (i >> 3) & 63, ks = (i >> 9) & 1, nt = i >> 10;
        int r = ks * 32 + (ln >> 4) * 8 + j;
        w3S[i] = (__bf16)w3[r * 256 + nt * 16 + (ln & 15)];
    }
    if (i < 110592) {
        int j = i & 7, ln = (i >> 3) & 63, ks = (i >> 9) & 1, nt = (i >> 10) & 3, k = i >> 12;
        int c = ks * 32 + (ln >> 4) * 8 + j;
        int o = nt * 16 + (ln & 15);
        w2S[i] = (__bf16)w2[(k * 64 + c) * 64 + o];
    }
}

// ---------------------------------------------------------------------------
// K1: y1 = x @ w1 (bf16, coalesced via LDS transpose); col partials for
// [w1|wp] (320 cols). B (wA, 80KB) staged in LDS in two 40KB halves.
// ---------------------------------------------------------------------------
__global__ __launch_bounds__(256) void k1(const float* __restrict__ x,
                                          const __bf16* __restrict__ wA,
                                          __bf16* __restrict__ y1,
                                          float* __restrict__ p1) {
    __shared__ __align__(16) __bf16 bs[20480];     // 40 KB B half
    __shared__ __align__(16) __bf16 yl[64][72];    // 9 KB y1 transpose tile
    int blk = blockIdx.x, tid = threadIdx.x;
    int wave = tid >> 6, lane = tid & 63, l15 = lane & 15, lg = lane >> 4;

#pragma unroll
    for (int r = 0; r < 10; r++) {
        const char* g = (const char*)wA + r * 4096 + wave * 1024 + lane * 16;
        char* l = (char*)bs + r * 4096 + wave * 1024;
        GLDS(g, l);
    }

    int row = blk * 64 + wave * 16 + l15;
    const float* xr = x + (size_t)row * 128 + lg * 8;
    bf16_8 a[4];
#pragma unroll
    for (int ks = 0; ks < 4; ks++) {
        float4 f0 = *(const float4*)(xr + ks * 32);
        float4 f1 = *(const float4*)(xr + ks * 32 + 4);
        bf16_8 t;
        t[0] = (__bf16)f0.x; t[1] = (__bf16)f0.y; t[2] = (__bf16)f0.z; t[3] = (__bf16)f0.w;
        t[4] = (__bf16)f1.x; t[5] = (__bf16)f1.y; t[6] = (__bf16)f1.z; t[7] = (__bf16)f1.w;
        a[ks] = t;
    }

    f32x4 acc[20];
#pragma unroll
    for (int nt = 0; nt < 20; nt++) acc[nt] = (f32x4){0.f, 0.f, 0.f, 0.f};

    __syncthreads();
#pragma unroll
    for (int nt = 0; nt < 10; nt++) {
#pragma unroll
        for (int ks = 0; ks < 4; ks++) {
            bf16_8 b = *(const bf16_8*)(bs + ((nt * 4 + ks) * 64 + lane) * 8);
            acc[nt] = __builtin_amdgcn_mfma_f32_16x16x32_bf16(a[ks], b, acc[nt], 0, 0, 0);
        }
    }
    __syncthreads();

#pragma unroll
    for (int r = 0; r < 10; r++) {
        const char* g = (const char*)wA + 40960 + r * 4096 + wave * 1024 + lane * 16;
        char* l = (char*)bs + r * 4096 + wave * 1024;
        GLDS(g, l);
    }
#pragma unroll
    for (int nt = 0; nt < 4; nt++)
#pragma unroll
        for (int r4 = 0; r4 < 4; r4++)
            yl[wave * 16 + lg * 4 + r4][nt * 16 + l15] = (__bf16)acc[nt][r4];
    __syncthreads();

#pragma unroll
    for (int p = 0; p < 2; p++) {
        int rr = p * 32 + (tid >> 3), c8 = tid & 7;
        bf16_8 v = *(const bf16_8*)&yl[rr][c8 * 8];
        *(bf16_8*)(y1 + (size_t)(blk * 64 + rr) * 64 + c8 * 8) = v;
    }

#pragma unroll
    for (int nt = 10; nt < 20; nt++) {
#pragma unroll
        for (int ks = 0; ks < 4; ks++) {
            bf16_8 b = *(const bf16_8*)(bs + (((nt - 10) * 4 + ks) * 64 + lane) * 8);
            acc[nt] = __builtin_amdgcn_mfma_f32_16x16x32_bf16(a[ks], b, acc[nt], 0, 0, 0);
        }
    }

    float* prow = p1 + ((size_t)blk * 4 + wave) * 640;
#pragma unroll
    for (int nt = 0; nt < 20; nt++) {
        float s = 0.f, q = 0.f;
#pragma unroll
        for (int r4 = 0; r4 < 4; r4++) { float v = acc[nt][r4]; s += v; q += v * v; }
        s += __shfl_xor(s, 16); s += __shfl_xor(s, 32);
        q += __shfl_xor(q, 16); q += __shfl_xor(q, 32);
        if (lane < 16) { prow[nt * 16 + l15] = s; prow[320 + nt * 16 + l15] = q; }
    }
}

// ---------------------------------------------------------------------------
__global__ void k_red(const float* __restrict__ part, float* __restrict__ outp,
                      int nrows, int chunk) {
    int width = blockDim.x;
    int b = blockIdx.x, t = threadIdx.x;
    int r0 = b * chunk, r1 = r0 + chunk;
    if (r1 > nrows) r1 = nrows;
    float s = 0.f;
    for (int r = r0; r < r1; r++) s += part[(size_t)r * width + t];
    outp[(size_t)b * width + t] = s;
}

// ---------------------------------------------------------------------------
__global__ void k_fin(const float* __restrict__ psum, const float* __restrict__ psq,
                      int nrows, int rowstride,
                      const float* __restrict__ g, const float* __restrict__ b,
                      float* __restrict__ s_out, float* __restrict__ t_out) {
    int c = blockIdx.x;
    float s = 0.f, q = 0.f;
    for (int r = threadIdx.x; r < nrows; r += blockDim.x) {
        size_t o = (size_t)r * rowstride + c;
        s += psum[o]; q += psq[o];
    }
#pragma unroll
    for (int off = 32; off; off >>= 1) { s += __shfl_xor(s, off); q += __shfl_xor(q, off); }
    __shared__ float ls[4], lq[4];
    int wv = threadIdx.x >> 6;
    if ((threadIdx.x & 63) == 0) { ls[wv] = s; lq[wv] = q; }
    __syncthreads();
    if (threadIdx.x == 0) {
        s = ls[0] + ls[1] + ls[2] + ls[3];
        q = lq[0] + lq[1] + lq[2] + lq[3];
        float m = s * (1.f / (float)NN);
        float v = q * (1.f / (float)NN) - m * m;
        float rs = rsqrtf(v + 1e-3f);
        float sc = g[c] * rs;
        s_out[c] = sc; t_out[c] = b[c] - m * sc;
    }
}

// ---------------------------------------------------------------------------
// K_h1: h1 = relu(s1*y1 + t1) bf16 (one pass; keeps BN out of k3's loop)
// ---------------------------------------------------------------------------
__global__ __launch_bounds__(256) void k_h1(const __bf16* __restrict__ y1,
                                            const float* __restrict__ coef,
                                            __bf16* __restrict__ h1) {
    int i = blockIdx.x * 256 + threadIdx.x;
    int c0 = (i * 8) & 63;
    bf16_8 v = *(const bf16_8*)(y1 + (size_t)i * 8);
    bf16_8 o;
#pragma unroll
    for (int j = 0; j < 8; j++) {
        float f = (float)v[j] * coef[c0 + j] + coef[64 + c0 + j];
        o[j] = (__bf16)fmaxf(f, 0.f);
    }
    *(bf16_8*)(h1 + (size_t)i * 8) = o;
}

// ---------------------------------------------------------------------------
// K3 v4: y2 = einsum(gather(h1), w2). Pure gather+MFMA loop; w2 double-
// buffered in LDS; gather rows prefetched 2 k-steps ahead.
// ---------------------------------------------------------------------------
__global__ __launch_bounds__(256) void k3(const int* __restrict__ neigh,
                                          const __bf16* __restrict__ h1,
                                          const __bf16* __restrict__ w2S,
                                          __bf16* __restrict__ y2,
                                          float* __restrict__ p2) {
    __shared__ int nl[64 * 27];
    __shared__ __align__(16) __bf16 bsb[2][4096];

    int blk = blockIdx.x, tid = threadIdx.x;
    int wave = tid >> 6, lane = tid & 63, l15 = lane & 15, lg = lane >> 4;

    for (int i = tid; i < 64 * 27; i += 256) nl[i] = neigh[(size_t)blk * 1728 + i];

#pragma unroll
    for (int r = 0; r < 2; r++) {
        const char* g = (const char*)w2S + r * 4096 + wave * 1024 + lane * 16;
        char* l = (char*)&bsb[0][0] + r * 4096 + wave * 1024;
        GLDS(g, l);
    }
    __syncthreads();   // nl ready + bsb[0] staged

    int row27 = (wave * 16 + l15) * 27;
    int i0 = nl[row27 + 0], i1 = nl[row27 + 1];
    const __bf16* hp0 = h1 + (size_t)i0 * 64 + lg * 8;
    const __bf16* hp1 = h1 + (size_t)i1 * 64 + lg * 8;
    bf16_8 c0 = *(const bf16_8*)hp0, c1 = *(const bf16_8*)(hp0 + 32);
    bf16_8 n0 = *(const bf16_8*)hp1, n1 = *(const bf16_8*)(hp1 + 32);

    f32x4 acc[4];
#pragma unroll
    for (int nt = 0; nt < 4; nt++) acc[nt] = (f32x4){0.f, 0.f, 0.f, 0.f};

    int cur = 0;
    for (int k = 0; k < 27; k++) {
        if (k < 26) {
#pragma unroll
            for (int r = 0; r < 2; r++) {
                const char* g = (const char*)w2S + (size_t)(k + 1) * 8192 + r * 4096 + wave * 1024 + lane * 16;
                char* l = (char*)&bsb[cur ^ 1][0] + r * 4096 + wave * 1024;
                GLDS(g, l);
            }
        }
        bf16_8 p0 = c0, p1 = c1;
        if (k < 25) {
            int i2 = nl[row27 + k + 2];
            const __bf16* hp2 = h1 + (size_t)i2 * 64 + lg * 8;
            p0 = *(const bf16_8*)hp2;
            p1 = *(const bf16_8*)(hp2 + 32);
        }
        const __bf16* bb = &bsb[cur][0];
#pragma unroll
        for (int nt = 0; nt < 4; nt++) {
            bf16_8 b0 = *(const bf16_8*)(bb + ((nt * 2 + 0) * 64 + lane) * 8);
            bf16_8 b1 = *(const bf16_8*)(bb + ((nt * 2 + 1) * 64 + lane) * 8);
            acc[nt] = __builtin_amdgcn_mfma_f32_16x16x32_bf16(c0, b0, acc[nt], 0, 0, 0);
            acc[nt] = __builtin_amdgcn_mfma_f32_16x16x32_bf16(c1, b1, acc[nt], 0, 0, 0);
        }
        __syncthreads();   // staging done + reads of bsb[cur] done
        c0 = n0; c1 = n1; n0 = p0; n1 = p1;
        cur ^= 1;
    }

#pragma unroll
    for (int nt = 0; nt < 4; nt++)
#pragma unroll
        for (int r4 = 0; r4 < 4; r4++) {
            int gr = blk * 64 + wave * 16 + lg * 4 + r4;
            y2[(size_t)gr * 64 + nt * 16 + l15] = (__bf16)acc[nt][r4];
        }

    float* prow = p2 + ((size_t)blk * 4 + wave) * 128;
#pragma unroll
    for (int nt = 0; nt < 4; nt++) {
        float s = 0.f, q = 0.f;
#pragma unroll
        for (int r4 = 0; r4 < 4; r4++) { float v = acc[nt][r4]; s += v; q += v * v; }
        s += __shfl_xor(s, 16); s += __shfl_xor(s, 32);
        q += __shfl_xor(q, 16); q += __shfl_xor(q, 32);
        if (lane < 16) { prow[nt * 16 + l15] = s; prow[64 + nt * 16 + l15] = q; }
    }
}

// ---------------------------------------------------------------------------
// K5m: bn3 stats without materializing y3/h2b:
//   colsum[c] = sum_n h2b[n][c] ;  M = h2b^T h2b  (64x64, MFMA f32 accum)
// h2b recomputed from y2 on the fly. A-frag of h^T == B-frag of h (same LDS
// addressing). 512 blocks x ~6 tiles, per-block partial M written out.
// ---------------------------------------------------------------------------
__global__ __launch_bounds__(256) void k5m(const __bf16* __restrict__ y2,
                                           const float* __restrict__ coef,
                                           float* __restrict__ Mpart,
                                           float* __restrict__ cspart) {
    __shared__ __align__(16) __bf16 hl[64][80];   // pad 16 -> conflict-free u16 frags
    int blk = blockIdx.x, tid = threadIdx.x;
    int wave = tid >> 6, lane = tid & 63, l15 = lane & 15, lg = lane >> 4;

    float s0[8], t0[8], s1[8], t1[8];
#pragma unroll
    for (int j = 0; j < 8; j++) {
        int c = lg * 8 + j;
        s0[j] = coef[128 + c];      t0[j] = coef[192 + c];
        s1[j] = coef[160 + c];      t1[j] = coef[224 + c];
    }
    bf16_8 ones;
#pragma unroll
    for (int j = 0; j < 8; j++) ones[j] = (__bf16)1.0f;

    f32x4 acc[4], acc1;
#pragma unroll
    for (int nt = 0; nt < 4; nt++) acc[nt] = (f32x4){0.f, 0.f, 0.f, 0.f};
    acc1 = (f32x4){0.f, 0.f, 0.f, 0.f};

    for (int t = blk; t < NBLK; t += 512) {
        const __bf16* yp = y2 + ((size_t)t * 64 + wave * 16 + l15) * 64 + lg * 8;
        bf16_8 v0 = *(const bf16_8*)yp, v1 = *(const bf16_8*)(yp + 32);
        bf16_8 h0, h2;
#pragma unroll
        for (int j = 0; j < 8; j++) {
            h0[j] = (__bf16)fmaxf((float)v0[j] * s0[j] + t0[j], 0.f);
            h2[j] = (__bf16)fmaxf((float)v1[j] * s1[j] + t1[j], 0.f);
        }
        __syncthreads();   // previous-iteration frag reads done
        *(bf16_8*)&hl[wave * 16 + l15][lg * 8] = h0;
        *(bf16_8*)&hl[wave * 16 + l15][32 + lg * 8] = h2;
        __syncthreads();   // tile visible

        bf16_8 fa[2], fb[4][2];
#pragma unroll
        for (int ks = 0; ks < 2; ks++)
#pragma unroll
            for (int j = 0; j < 8; j++)
                fa[ks][j] = hl[ks * 32 + lg * 8 + j][wave * 16 + l15];
#pragma unroll
        for (int nt = 0; nt < 4; nt++)
#pragma unroll
            for (int ks = 0; ks < 2; ks++)
#pragma unroll
                for (int j = 0; j < 8; j++)
                    fb[nt][ks][j] = hl[ks * 32 + lg * 8 + j][nt * 16 + l15];

#pragma unroll
        for (int nt = 0; nt < 4; nt++)
#pragma unroll
            for (int ks = 0; ks < 2; ks++)
                acc[nt] = __builtin_amdgcn_mfma_f32_16x16x32_bf16(fa[ks], fb[nt][ks], acc[nt], 0, 0, 0);
#pragma unroll
        for (int ks = 0; ks < 2; ks++)
            acc1 = __builtin_amdgcn_mfma_f32_16x16x32_bf16(ones, fa[ks], acc1, 0, 0, 0);
    }

#pragma unroll
    for (int nt = 0; nt < 4; nt++)
#pragma unroll
        for (int r4 = 0; r4 < 4; r4++)
            Mpart[((size_t)blk * 64 + wave * 16 + lg * 4 + r4) * 64 + nt * 16 + l15] = acc[nt][r4];
    if (lg == 0) cspart[blk * 64 + wave * 16 + l15] = acc1[0];
}

// ---------------------------------------------------------------------------
__global__ void k_redM(const float* __restrict__ Mpart, const float* __restrict__ cspart,
                       float* __restrict__ Mout, float* __restrict__ csout) {
    int b = blockIdx.x, t = threadIdx.x;
    if (b < 16) {
        int col = b * 256 + t;
        float s = 0.f;
        for (int r = 0; r < 512; r++) s += Mpart[(size_t)r * 4096 + col];
        Mout[col] = s;
    } else if (t < 64) {
        float s = 0.f;
        for (int r = 0; r < 512; r++) s += cspart[r * 64 + t];
        csout[t] = s;
    }
}

// ---------------------------------------------------------------------------
// K_fin3: bn3 coefs from (M, colsum): mean_o = cs.w3b_o/N ;
// E[y3^2]_o = w3b_o^T M w3b_o / N. Fold with sp/tp into cr/cb.
// ---------------------------------------------------------------------------
__global__ void k_fin3(const float* __restrict__ M, const float* __restrict__ cs,
                       const float* __restrict__ w3, const float* __restrict__ g3,
                       const float* __restrict__ b3, float* __restrict__ coef) {
    int o = blockIdx.x, t = threadIdx.x;
    __shared__ float w3l[64];
    if (t < 64) w3l[t] = (float)(__bf16)w3[t * 256 + o];
    __syncthreads();
    int c = t >> 2, c0 = (t & 3) * 16;
    float q = 0.f;
#pragma unroll
    for (int j = 0; j < 16; j++) q += M[c * 64 + c0 + j] * w3l[c0 + j];
    q *= w3l[c];
    float m = (t < 64) ? cs[t] * w3l[t] : 0.f;
#pragma unroll
    for (int off = 32; off; off >>= 1) { q += __shfl_xor(q, off); m += __shfl_xor(m, off); }
    __shared__ float lq[4], lm[4];
    int wv = t >> 6;
    if ((t & 63) == 0) { lq[wv] = q; lm[wv] = m; }
    __syncthreads();
    if (t == 0) {
        float Q = lq[0] + lq[1] + lq[2] + lq[3];
        float S = lm[0] + lm[1] + lm[2] + lm[3];
        float mean = S * (1.f / (float)NN);
        float var = Q * (1.f / (float)NN) - mean * mean;
        float rs = rsqrtf(var + 1e-3f);
        float s3 = g3[o] * rs;
        float t3 = b3[o] - mean * s3;
        coef[768 + o] = s3 / coef[256 + o];
        coef[1280 + o] = t3 + coef[512 + o];
    }
}

// ---------------------------------------------------------------------------
// K7: out = relu(s3*(h2b@w3) + t3 + sp*(x@wp) + tp); h2b recomputed from y2.
// B staged in LDS per 128-col half; f32 LDS-transpose epilogue, dwordx4 stores.
// ---------------------------------------------------------------------------
__global__ __launch_bounds__(256) void k7(const float* __restrict__ x,
                                          const __bf16* __restrict__ y2,
                                          const __bf16* __restrict__ w3S,
                                          const __bf16* __restrict__ wA,
                                          const float* __restrict__ coef,
                                          float* __restrict__ out) {
    __shared__ __align__(16) char smem[49152];
    int blk = blockIdx.x, tid = threadIdx.x;
    int wave = tid >> 6, lane = tid & 63, l15 = lane & 15, lg = lane >> 4;
    int row = blk * 64 + wave * 16 + l15;

    const __bf16* bsw3 = (const __bf16*)smem;
    const __bf16* bswp = (const __bf16*)(smem + 16384);
    float* el = (float*)smem;

    // A fragments: h2b recomputed from y2 + bn2 coefs
    const __bf16* yp = y2 + (size_t)row * 64 + lg * 8;
    bf16_8 v0 = *(const bf16_8*)yp, v1 = *(const bf16_8*)(yp + 32);
    bf16_8 ah0, ah1;
#pragma unroll
    for (int j = 0; j < 8; j++) {
        int c = lg * 8 + j;
        ah0[j] = (__bf16)fmaxf((float)v0[j] * coef[128 + c] + coef[192 + c], 0.f);
        ah1[j] = (__bf16)fmaxf((float)v1[j] * coef[160 + c] + coef[224 + c], 0.f);
    }
    const float* xr = x + (size_t)row * 128 + lg * 8;
    bf16_8 ax[4];
#pragma unroll
    for (int ks = 0; ks < 4; ks++) {
        float4 f0 = *(const float4*)(xr + ks * 32);
        float4 f1 = *(const float4*)(xr + ks * 32 + 4);
        bf16_8 t;
        t[0] = (__bf16)f0.x; t[1] = (__bf16)f0.y; t[2] = (__bf16)f0.z; t[3] = (__bf16)f0.w;
        t[4] = (__bf16)f1.x; t[5] = (__bf16)f1.y; t[6] = (__bf16)f1.z; t[7] = (__bf16)f1.w;
        ax[ks] = t;
    }

#pragma unroll
    for (int h = 0; h < 2; h++) {
#pragma unroll
        for (int r = 0; r < 4; r++) {
            const char* g = (const char*)w3S + h * 16384 + r * 4096 + wave * 1024 + lane * 16;
            char* l = smem + r * 4096 + wave * 1024;
            GLDS(g, l);
        }
#pragma unroll
        for (int r = 0; r < 8; r++) {
            const char* g = (const char*)wA + (4 + h * 8) * 4096 + r * 4096 + wave * 1024 + lane * 16;
            char* l = smem + 16384 + r * 4096 + wave * 1024;
            GLDS(g, l);
        }
        __syncthreads();

        f32x4 acc[8];
#pragma unroll
        for (int nt = 0; nt < 8; nt++) acc[nt] = (f32x4){0.f, 0.f, 0.f, 0.f};

#pragma unroll
        for (int nt = 0; nt < 8; nt++) {
            bf16_8 b0 = *(const bf16_8*)(bsw3 + ((nt * 2 + 0) * 64 + lane) * 8);
            bf16_8 b1 = *(const bf16_8*)(bsw3 + ((nt * 2 + 1) * 64 + lane) * 8);
            acc[nt] = __builtin_amdgcn_mfma_f32_16x16x32_bf16(ah0, b0, acc[nt], 0, 0, 0);
            acc[nt] = __builtin_amdgcn_mfma_f32_16x16x32_bf16(ah1, b1, acc[nt], 0, 0, 0);
        }
#pragma unroll
        for (int nt = 0; nt < 8; nt++) acc[nt] *= coef[768 + h * 128 + nt * 16 + l15];
#pragma unroll
        for (int nt = 0; nt < 8; nt++) {
#pragma unroll
            for (int ks = 0; ks < 4; ks++) {
                bf16_8 b = *(const bf16_8*)(bswp + ((nt * 4 + ks) * 64 + lane) * 8);
                acc[nt] = __builtin_amdgcn_mfma_f32_16x16x32_bf16(ax[ks], b, acc[nt], 0, 0, 0);
            }
        }
        __syncthreads();

#pragma unroll
        for (int nt = 0; nt < 8; nt++) {
            int gc = h * 128 + nt * 16 + l15;
            float cs = coef[256 + gc], cb = coef[1280 + gc];
#pragma unroll
            for (int r4 = 0; r4 < 4; r4++)
                el[(wave * 16 + lg * 4 + r4) * 132 + nt * 16 + l15] =
                    fmaxf(acc[nt][r4] * cs + cb, 0.f);
        }
        __syncthreads();
#pragma unroll
        for (int p = 0; p < 8; p++) {
            int rr = p * 8 + (tid >> 5), c4 = tid & 31;
            float4 v = *(const float4*)&el[rr * 132 + c4 * 4];
            *(float4*)(out + (size_t)(blk * 64 + rr) * 256 + h * 128 + c4 * 4) = v;
        }
        __syncthreads();
    }
}

// ---------------------------------------------------------------------------
extern "C" void kernel_launch(void* const* d_in, const int* in_sizes, int n_in,
                              void* d_out, int out_size, void* d_ws, size_t ws_size,
                              hipStream_t stream) {
    const float* x     = (const float*)d_in[0];
    const int*   neigh = (const int*)d_in[1];
    const float* w1 = (const float*)d_in[3];
    const float* g1 = (const float*)d_in[4];
    const float* b1 = (const float*)d_in[5];
    const float* w2 = (const float*)d_in[6];
    const float* g2 = (const float*)d_in[7];
    const float* b2 = (const float*)d_in[8];
    const float* w3 = (const float*)d_in[9];
    const float* g3 = (const float*)d_in[10];
    const float* b3 = (const float*)d_in[11];
    const float* wp = (const float*)d_in[12];
    const float* gp = (const float*)d_in[13];
    const float* bp = (const float*)d_in[14];
    float* out = (float*)d_out;

    char* ws = (char*)d_ws;
    __bf16* wA  = (__bf16*)(ws + OFF_WA);
    __bf16* w3S = (__bf16*)(ws + OFF_W3S);
    __bf16* w2S = (__bf16*)(ws + OFF_W2S);
    __bf16* y1  = (__bf16*)(ws + OFF_Y1);
    __bf16* y2  = (__bf16*)(ws + OFF_Y2);
    __bf16* h1  = (__bf16*)(ws + OFF_H1);
    float* p1   = (float*)(ws + OFF_P1);
    float* p2   = (float*)(ws + OFF_P2);
    float* coef = (float*)(ws + OFF_COEF);
    float* pA1  = (float*)(ws + OFF_PA1);
    float* pA2  = (float*)(ws + OFF_PA2);
    float* Mp   = (float*)(ws + OFF_MP);
    float* csp  = (float*)(ws + OFF_CSP);
    float* Mm   = (float*)(ws + OFF_MM);
    float* csv  = (float*)(ws + OFF_CS);

    k_prep<<<432, 256, 0, stream>>>(w1, w2, w3, wp, wA, w2S, w3S);

    k1<<<NBLK, 256, 0, stream>>>(x, wA, y1, p1);
    k_red<<<125, 640, 0, stream>>>(p1, pA1, 12500, 100);
    k_fin<<<64, 256, 0, stream>>>(pA1, pA1 + 320, 125, 640, g1, b1, coef + 0, coef + 64);
    k_fin<<<256, 256, 0, stream>>>(pA1 + 64, pA1 + 384, 125, 640, gp, bp, coef + 256, coef + 512);

    k_h1<<<6250, 256, 0, stream>>>(y1, coef, h1);

    k3<<<NBLK, 256, 0, stream>>>(neigh, h1, w2S, y2, p2);
    k_red<<<125, 128, 0, stream>>>(p2, pA2, 12500, 100);
    k_fin<<<64, 256, 0, stream>>>(pA2, pA2 + 64, 125, 128, g2, b2, coef + 128, coef + 192);

    k5m<<<512, 256, 0, stream>>>(y2, coef, Mp, csp);
    k_redM<<<17, 256, 0, stream>>>(Mp, csp, Mm, csv);
    k_fin3<<<256, 256, 0, stream>>>(Mm, csv, w3, g3, b3, coef);

    k7<<<NBLK, 256, 0, stream>>>(x, y2, w3S, wA, coef, out);
}